// Round 8
// baseline (324.555 us; speedup 1.0000x reference)
//
#include <hip/hip_runtime.h>
#include <stdint.h>

typedef unsigned short u16;
typedef __attribute__((ext_vector_type(8))) short short8;
typedef __attribute__((ext_vector_type(4))) float f32x4;
typedef __attribute__((ext_vector_type(16))) float f32x16;

#define GPTR(p) ((const __attribute__((address_space(1))) void*)(p))
#define SPTR(p) ((__attribute__((address_space(3))) void*)(p))
#define GLDS16(g, l) __builtin_amdgcn_global_load_lds(GPTR(g), SPTR(l), 16, 0, 0)

static __device__ __forceinline__ float bf2f(u16 u) {
  union { unsigned int i; float f; } c; c.i = ((unsigned int)u) << 16; return c.f;
}
static __device__ __forceinline__ u16 f2bf(float f) {
  union { float f; unsigned int u; } c; c.f = f;
  unsigned int r = 0x7fffu + ((c.u >> 16) & 1u);
  return (u16)((c.u + r) >> 16);
}
static __device__ __forceinline__ unsigned cvtpk(float a, float b) {
  unsigned r;
  asm volatile("v_cvt_pk_bf16_f32 %0, %1, %2" : "=v"(r) : "v"(a), "v"(b));
  return r;
}
static __device__ __forceinline__ int swz4(int row, int c) { return c ^ ((row >> 1) & 3); }

// ---------------- LayerNorm: f32 (rows of 1024) -> bf16 ----------------
__global__ __launch_bounds__(256) void ln_kernel(
    const float* __restrict__ x, const float* __restrict__ ctx,
    const float* __restrict__ g, const float* __restrict__ b,
    const float* __restrict__ cg, const float* __restrict__ cb,
    u16* __restrict__ xn, u16* __restrict__ cn)
{
  const int row = blockIdx.x;
  const float* src; const float* gg; const float* bb; u16* dst;
  if (row < 4096) { src = x + (size_t)row * 1024; gg = g;  bb = b;  dst = xn + (size_t)row * 1024; }
  else            { src = ctx + (size_t)(row - 4096) * 1024; gg = cg; bb = cb; dst = cn + (size_t)(row - 4096) * 1024; }
  const int t = threadIdx.x;
  float4 v = *(const float4*)&src[t * 4];
  float s  = v.x + v.y + v.z + v.w;
  float s2 = v.x * v.x + v.y * v.y + v.z * v.z + v.w * v.w;
  #pragma unroll
  for (int off = 1; off < 64; off <<= 1) { s += __shfl_xor(s, off); s2 += __shfl_xor(s2, off); }
  __shared__ float ls[4], ls2[4];
  const int w = t >> 6;
  if ((t & 63) == 0) { ls[w] = s; ls2[w] = s2; }
  __syncthreads();
  s  = ls[0] + ls[1] + ls[2] + ls[3];
  s2 = ls2[0] + ls2[1] + ls2[2] + ls2[3];
  const float mu   = s * (1.0f / 1024.0f);
  const float var  = s2 * (1.0f / 1024.0f) - mu * mu;
  const float rstd = rsqrtf(var + 1e-5f);
  float xv[4] = { v.x, v.y, v.z, v.w };
  u16 o[4];
  #pragma unroll
  for (int i = 0; i < 4; ++i)
    o[i] = f2bf((xv[i] - mu) * rstd * gg[t * 4 + i] + bb[t * 4 + i]);
  uint2 pv;
  pv.x = (unsigned)o[0] | ((unsigned)o[1] << 16);
  pv.y = (unsigned)o[2] | ((unsigned)o[3] << 16);
  *(uint2*)&dst[t * 4] = pv;
}

// ---------------- transpose+convert: f32 (R,C) -> bf16 (C,R) with out leading dim ----------------
__global__ __launch_bounds__(256) void transpose_k(
    const float* __restrict__ in, u16* __restrict__ out, int R, int C, int ldo, float scale)
{
  __shared__ float tile[64][65];
  const int c0 = blockIdx.x * 64, r0 = blockIdx.y * 64;
  const int t = threadIdx.x;
  const int tr = t >> 4, tc = (t & 15) * 4;
  #pragma unroll
  for (int i = 0; i < 4; ++i) {
    int r = tr + i * 16;
    float4 v = *(const float4*)&in[(size_t)(r0 + r) * C + c0 + tc];
    tile[r][tc + 0] = v.x; tile[r][tc + 1] = v.y; tile[r][tc + 2] = v.z; tile[r][tc + 3] = v.w;
  }
  __syncthreads();
  #pragma unroll
  for (int i = 0; i < 2; ++i) {
    int c  = (t >> 3) + i * 32;
    int rb = (t & 7) * 8;
    union { u16 s[8]; uint4 v; } pk;
    #pragma unroll
    for (int u = 0; u < 8; ++u) pk.s[u] = f2bf(tile[rb + u][c] * scale);
    *(uint4*)&out[(size_t)(c0 + c) * ldo + r0 + rb] = pk.v;
  }
}

// ---------------- Wff1 transpose with (a,gate) fragment interleave ----------------
__global__ __launch_bounds__(256) void transpose_ff1(
    const float* __restrict__ in, u16* __restrict__ out)
{
  __shared__ float tile[64][65];
  const int c0 = blockIdx.x * 64, r0 = blockIdx.y * 64;
  const int t = threadIdx.x;
  const int tr = t >> 4, tc = (t & 15) * 4;
  #pragma unroll
  for (int i = 0; i < 4; ++i) {
    int r = tr + i * 16;
    float4 v = *(const float4*)&in[(size_t)(r0 + r) * 8192 + c0 + tc];
    tile[r][tc + 0] = v.x; tile[r][tc + 1] = v.y; tile[r][tc + 2] = v.z; tile[r][tc + 3] = v.w;
  }
  __syncthreads();
  #pragma unroll
  for (int i = 0; i < 2; ++i) {
    int c  = (t >> 3) + i * 32;
    int rb = (t & 7) * 8;
    const int gc = c0 + c;
    int j, add16;
    if (gc < 4096) { j = gc; add16 = 0; } else { j = gc - 4096; add16 = 16; }
    const int row = 1024 + ((j >> 7) << 8) + (((j >> 5) & 3) << 6) + (((j >> 4) & 1) << 5) + add16 + (j & 15);
    union { u16 s[8]; uint4 v; } pk;
    #pragma unroll
    for (int u = 0; u < 8; ++u) pk.s[u] = f2bf(tile[rb + u][c]);
    *(uint4*)&out[(size_t)row * 1024 + r0 + rb] = pk.v;
  }
}

// =============== 8-phase 256x256 GEMM (BK=64, 8 waves, 2-deep dbuf) ===============
// ORDER 0: bm-fastest within XCD chunk (B-panel strip L2-resident; for big-B GEMMs)
// ORDER 1: bn-fastest within XCD chunk (A-panels XCD-exclusive; for big-A GEMMs)
#define MM1(MQ, M, NN, BF) acc[MQ][M][NN] = __builtin_amdgcn_mfma_f32_16x16x32_bf16(af##M, BF, acc[MQ][M][NN], 0, 0, 0)
#define MFMA16(MQ, KS) \
  MM1(MQ,0,0,bf##KS##0); MM1(MQ,0,1,bf##KS##1); MM1(MQ,0,2,bf##KS##2); MM1(MQ,0,3,bf##KS##3); \
  MM1(MQ,1,0,bf##KS##0); MM1(MQ,1,1,bf##KS##1); MM1(MQ,1,2,bf##KS##2); MM1(MQ,1,3,bf##KS##3); \
  MM1(MQ,2,0,bf##KS##0); MM1(MQ,2,1,bf##KS##1); MM1(MQ,2,2,bf##KS##2); MM1(MQ,2,3,bf##KS##3); \
  MM1(MQ,3,0,bf##KS##0); MM1(MQ,3,1,bf##KS##1); MM1(MQ,3,2,bf##KS##2); MM1(MQ,3,3,bf##KS##3)

#define SG_A(SBUF, H, KT) do { \
    GLDS16(gA[H][0] + ((size_t)(KT) << 6), SBUF + ((H) * 64 + w16o) * 64); \
    GLDS16(gA[H][1] + ((size_t)(KT) << 6), SBUF + ((H) * 64 + w16o + 8) * 64); \
  } while (0)
#define SG_B(SBUF, H, KT) do { \
    GLDS16(gB[H][0] + ((size_t)(KT) << 6), SBUF + ((H) * 128 + w16o2) * 64); \
    GLDS16(gB[H][1] + ((size_t)(KT) << 6), SBUF + ((H) * 128 + w16o2 + 8) * 64); \
  } while (0)

#define DS_B(PB_) do { \
  bf00 = *(const short8*)(PB_ + 0    + cks0); bf01 = *(const short8*)(PB_ + 1024 + cks0); \
  bf02 = *(const short8*)(PB_ + 2048 + cks0); bf03 = *(const short8*)(PB_ + 3072 + cks0); \
  bf10 = *(const short8*)(PB_ + 0    + cks1); bf11 = *(const short8*)(PB_ + 1024 + cks1); \
  bf12 = *(const short8*)(PB_ + 2048 + cks1); bf13 = *(const short8*)(PB_ + 3072 + cks1); \
} while (0)

#define P_CORE(PA_, MQ, KS, STAGE_STMT, PREB_STMT, GATE_STMT) do { \
  af0 = *(const short8*)(PA_ + (MQ) * 4096 + 0    + cks##KS); \
  af1 = *(const short8*)(PA_ + (MQ) * 4096 + 1024 + cks##KS); \
  af2 = *(const short8*)(PA_ + (MQ) * 4096 + 2048 + cks##KS); \
  af3 = *(const short8*)(PA_ + (MQ) * 4096 + 3072 + cks##KS); \
  STAGE_STMT; \
  PREB_STMT; \
  __builtin_amdgcn_s_barrier(); \
  asm volatile("s_waitcnt lgkmcnt(0)" ::: "memory"); \
  __builtin_amdgcn_s_setprio(1); \
  MFMA16(MQ, KS); \
  __builtin_amdgcn_s_setprio(0); \
  GATE_STMT; \
  __builtin_amdgcn_s_barrier(); \
} while (0)

#define GATE6 asm volatile("s_waitcnt vmcnt(6)" ::: "memory")
#define GATE0 asm volatile("s_waitcnt vmcnt(0)" ::: "memory")
#define HINT8 asm volatile("s_waitcnt lgkmcnt(8)" ::: "memory")

template<int MODE, int ORDER>
__global__ __launch_bounds__(512, 2) void gemm8p(
    const u16* __restrict__ A, const u16* __restrict__ BT, void* __restrict__ C,
    void* __restrict__ C2, int M, int N, int Ktot, int Kslice)
{
  __shared__ u16 sh[2][2][16384]; // [buf][A/B][256*64]
  const int nbn = N >> 8, nbm = M >> 8;
  const int nwg = gridDim.x;
  const int bid = blockIdx.x;
  const int o = (bid & 7) * (nwg >> 3) + (bid >> 3);  // chunked bijective XCD map (nwg%8==0)
  int bm, bn;
  if constexpr (ORDER == 0) { bm = o % nbm; bn = o / nbm; }  // B-strip per XCD
  else                      { bn = o % nbn; bm = o / nbn; }  // A-panels per XCD
  const int kbase = blockIdx.y * Kslice;
  const int NI = Kslice >> 7;

  const int t = threadIdx.x, w = t >> 6, lane = t & 63;
  const int wr = w >> 2, wc = w & 3;
  const int lr = lane & 15, lg = lane >> 4;
  const int r8 = lane >> 3, ch = lane & 7;
  const int clog = ch ^ r8;
  const int w16o  = w * 16 + ((w >= 4) ? 64 : 0);
  const int w16o2 = w * 16;

  const u16* gA[2][2]; const u16* gB[2][2];
  #pragma unroll
  for (int h = 0; h < 2; ++h)
    #pragma unroll
    for (int qq = 0; qq < 2; ++qq) {
      gA[h][qq] = A  + (size_t)(bm * 256 + h * 64  + w16o  + qq * 8 + r8) * Ktot + kbase + clog * 8;
      gB[h][qq] = BT + (size_t)(bn * 256 + h * 128 + w16o2 + qq * 8 + r8) * Ktot + kbase + clog * 8;
    }
  u16* sA0 = &sh[0][0][0]; u16* sA1 = &sh[1][0][0];
  u16* sB0 = &sh[0][1][0]; u16* sB1 = &sh[1][1][0];
  const int cks0 = ((0 + lg) ^ (lr & 7)) * 8;
  const int cks1 = ((4 + lg) ^ (lr & 7)) * 8;
  const u16* pA_b0 = sA0 + (wr * 128 + lr) * 64;
  const u16* pA_b1 = sA1 + (wr * 128 + lr) * 64;
  const u16* pB_b0 = sB0 + (wc * 64 + lr) * 64;
  const u16* pB_b1 = sB1 + (wc * 64 + lr) * 64;

  f32x4 acc[2][4][4];
  const f32x4 z4 = { 0.f, 0.f, 0.f, 0.f };
  #pragma unroll
  for (int a = 0; a < 2; ++a)
    #pragma unroll
    for (int b = 0; b < 4; ++b)
      #pragma unroll
      for (int c = 0; c < 4; ++c) acc[a][b][c] = z4;
  short8 af0, af1, af2, af3;
  short8 bf00, bf01, bf02, bf03, bf10, bf11, bf12, bf13;

  SG_B(sB0, 0, 0); SG_B(sB0, 1, 0); SG_A(sA0, 0, 0); SG_A(sA0, 1, 0);
  SG_B(sB1, 0, 1); SG_B(sB1, 1, 1); SG_A(sA1, 0, 1);
  GATE6;
  __builtin_amdgcn_s_barrier();

  for (int i = 0; i < NI; ++i) {
    const int k2 = 2 * i;
    const bool st = (i < NI - 1);
    DS_B(pB_b0);
    P_CORE(pA_b0, 0, 0, SG_A(sA1, 1, k2 + 1), HINT8, );
    P_CORE(pA_b0, 1, 0, if (st) SG_B(sB0, 0, k2 + 2), , );
    P_CORE(pA_b0, 0, 1, if (st) SG_B(sB0, 1, k2 + 2), , );
    P_CORE(pA_b0, 1, 1, if (st) SG_A(sA0, 0, k2 + 2), ,
           if (st) { GATE6; } else { GATE0; });
    DS_B(pB_b1);
    P_CORE(pA_b1, 0, 0, if (st) SG_A(sA0, 1, k2 + 2), HINT8, );
    P_CORE(pA_b1, 1, 0, if (st) SG_B(sB1, 0, k2 + 3), , );
    P_CORE(pA_b1, 0, 1, if (st) SG_B(sB1, 1, k2 + 3), , );
    P_CORE(pA_b1, 1, 1, if (st) SG_A(sA1, 0, k2 + 3), ,
           if (st) { GATE6; });
  }

  if constexpr (MODE == 1) {
    float* Co = (float*)C + (size_t)blockIdx.y * M * N;
    #pragma unroll
    for (int mq = 0; mq < 2; ++mq)
      #pragma unroll
      for (int m = 0; m < 4; ++m)
        #pragma unroll
        for (int n = 0; n < 4; ++n)
          #pragma unroll
          for (int rr = 0; rr < 4; ++rr) {
            const int row = bm * 256 + wr * 128 + mq * 64 + m * 16 + lg * 4 + rr;
            const int col = bn * 256 + wc * 64 + n * 16 + lr;
            Co[(size_t)row * N + col] = acc[mq][m][n][rr];
          }
  } else {
    if (bn < 4) {
      u16* Co = (u16*)C; // qbuf, stride 1024
      #pragma unroll
      for (int mq = 0; mq < 2; ++mq)
        #pragma unroll
        for (int m = 0; m < 4; ++m)
          #pragma unroll
          for (int n = 0; n < 4; ++n)
            #pragma unroll
            for (int rr = 0; rr < 4; ++rr) {
              const int row = bm * 256 + wr * 128 + mq * 64 + m * 16 + lg * 4 + rr;
              const int col = bn * 256 + wc * 64 + n * 16 + lr;
              Co[(size_t)row * 1024 + col] = f2bf(acc[mq][m][n][rr]);
            }
    } else {
      u16* Ho = (u16*)C2; // aoh, stride 5120, h starts at col 1024
      const int colb = 1024 + (bn - 4) * 128 + wc * 32 + lr;
      #pragma unroll
      for (int mq = 0; mq < 2; ++mq)
        #pragma unroll
        for (int m = 0; m < 4; ++m)
          #pragma unroll
          for (int rr = 0; rr < 4; ++rr) {
            const int row = bm * 256 + wr * 128 + mq * 64 + m * 16 + lg * 4 + rr;
            #pragma unroll
            for (int n2 = 0; n2 < 2; ++n2) {
              const float a = acc[mq][m][2 * n2][rr];
              const float gt = acc[mq][m][2 * n2 + 1][rr];
              const float h = a * gt / (1.0f + __expf(-gt));
              Ho[(size_t)row * 5120 + colb + n2 * 16] = f2bf(h);
            }
          }
    }
  }
}

// ---------------- split-K GEMM 128x128 (kv projection + final GEMM) ----------------
__global__ __launch_bounds__(256) void gemm_bt_sk(
    const u16* __restrict__ A, const u16* __restrict__ BT, float* __restrict__ Cp,
    int M, int N, int Kslice, int Ktot)
{
  __shared__ u16 As[128 * 32];
  __shared__ u16 Bs[128 * 32];
  const int bm = blockIdx.y, bn = blockIdx.x, z = blockIdx.z;
  const int t = threadIdx.x;
  const int w = t >> 6, lane = t & 63;
  const int wr = w >> 1, wc = w & 1;
  const int lr = lane & 15, lkc = lane >> 4;

  f32x4 acc[4][4];
  const f32x4 z4 = { 0.f, 0.f, 0.f, 0.f };
  #pragma unroll
  for (int mi = 0; mi < 4; ++mi)
    #pragma unroll
    for (int ni = 0; ni < 4; ++ni) acc[mi][ni] = z4;

  const int kbase = z * Kslice;
  const int i0 = t, i1 = t + 256;
  const int r0 = i0 >> 2, k0 = swz4(r0, i0 & 3) * 8;
  const int r1 = i1 >> 2, k1 = swz4(r1, i1 & 3) * 8;
  const u16* a0 = A + (size_t)(bm * 128 + r0) * Ktot + kbase + k0;
  const u16* a1 = A + (size_t)(bm * 128 + r1) * Ktot + kbase + k1;
  const u16* b0 = BT + (size_t)(bn * 128 + r0) * Ktot + kbase + k0;
  const u16* b1 = BT + (size_t)(bn * 128 + r1) * Ktot + kbase + k1;
  u16* As0 = As + (size_t)w * 512;
  u16* As1 = As + (size_t)(w + 4) * 512;
  u16* Bs0 = Bs + (size_t)w * 512;
  u16* Bs1 = Bs + (size_t)(w + 4) * 512;

  const int nk = Kslice >> 5;
  for (int kt = 0; kt < nk; ++kt) {
    __syncthreads();
    GLDS16(a0, As0); GLDS16(a1, As1); GLDS16(b0, Bs0); GLDS16(b1, Bs1);
    a0 += 32; a1 += 32; b0 += 32; b1 += 32;
    __syncthreads();
    short8 af[4], bf[4];
    #pragma unroll
    for (int mi = 0; mi < 4; ++mi) {
      int row = wr * 64 + mi * 16 + lr;
      af[mi] = *(const short8*)&As[row * 32 + swz4(row, lkc) * 8];
    }
    #pragma unroll
    for (int ni = 0; ni < 4; ++ni) {
      int row = wc * 64 + ni * 16 + lr;
      bf[ni] = *(const short8*)&Bs[row * 32 + swz4(row, lkc) * 8];
    }
    #pragma unroll
    for (int mi = 0; mi < 4; ++mi)
      #pragma unroll
      for (int ni = 0; ni < 4; ++ni)
        acc[mi][ni] = __builtin_amdgcn_mfma_f32_16x16x32_bf16(af[mi], bf[ni], acc[mi][ni], 0, 0, 0);
  }

  float* Cz = Cp + (size_t)z * M * N;
  const int row0 = bm * 128 + wr * 64, col0 = bn * 128 + wc * 64;
  const int rsub = (lane >> 4) * 4;
  #pragma unroll
  for (int mi = 0; mi < 4; ++mi)
    #pragma unroll
    for (int ni = 0; ni < 4; ++ni)
      #pragma unroll
      for (int r = 0; r < 4; ++r)
        Cz[(size_t)(row0 + mi * 16 + rsub + r) * N + (col0 + ni * 16 + lr)] = acc[mi][ni][r];
}

// ---------------- reduce 8 f32 partials (4096x128) -> bf16 ----------------
__global__ __launch_bounds__(256) void reduce_kv(const float* __restrict__ part, u16* __restrict__ out)
{
  const size_t base = ((size_t)blockIdx.x * 256 + threadIdx.x) * 4;
  f32x4 s = *(const f32x4*)&part[base];
  #pragma unroll
  for (int zz = 1; zz < 8; ++zz) {
    const f32x4 v = *(const f32x4*)&part[(size_t)zz * 524288 + base];
    s[0] += v[0]; s[1] += v[1]; s[2] += v[2]; s[3] += v[3];
  }
  uint2 pv;
  pv.x = (unsigned)f2bf(s[0]) | ((unsigned)f2bf(s[1]) << 16);
  pv.y = (unsigned)f2bf(s[2]) | ((unsigned)f2bf(s[3]) << 16);
  *(uint2*)&out[base] = pv;
}

// ---------------- out = sum of 4 f32 partials (4096x1024) ----------------
__global__ __launch_bounds__(256) void reduce_out(const float* __restrict__ part, float* __restrict__ out)
{
  const size_t base = ((size_t)blockIdx.x * 256 + threadIdx.x) * 4;
  f32x4 s = *(const f32x4*)&part[base];
  #pragma unroll
  for (int zz = 1; zz < 4; ++zz) {
    const f32x4 v = *(const f32x4*)&part[(size_t)zz * 4194304 + base];
    s[0] += v[0]; s[1] += v[1]; s[2] += v[2]; s[3] += v[3];
  }
  *(f32x4*)&out[base] = s;
}

// ---------------- flash cross-attention (multi-query: 1 KV head) ----------------
// 64 q-rows per wave (2 q32 tiles), 4 heads/block, grid (N/64, H/4, B) = 256 blocks.
__global__ __launch_bounds__(256) void attn_kernel(
    const u16* __restrict__ q, const u16* __restrict__ kv, u16* __restrict__ o)
{
  __shared__ u16 Ks[128 * 64];
  __shared__ u16 Vt[64 * 128];
  __shared__ u16 Ps[4][32 * 128];
  const int b = blockIdx.z, hb = blockIdx.y, qb = blockIdx.x;
  const int t = threadIdx.x, w = t >> 6, lane = t & 63;
  const int q32 = lane & 31, hl = lane >> 5;
  const int hd = hb * 4 + w;

  const size_t qbase = (size_t)b * 2048 + qb * 64;
  short8 qa[2][4];
  #pragma unroll
  for (int t32 = 0; t32 < 2; ++t32)
    #pragma unroll
    for (int dq = 0; dq < 4; ++dq)
      qa[t32][dq] = *(const short8*)&q[(qbase + t32 * 32 + q32) * 1024 + hd * 64 + dq * 16 + hl * 8];

  f32x16 oacc[2][2];
  #pragma unroll
  for (int i = 0; i < 2; ++i)
    #pragma unroll
    for (int j = 0; j < 2; ++j)
      #pragma unroll
      for (int r = 0; r < 16; ++r) oacc[i][j][r] = 0.f;
  float m_[2] = { -1e30f, -1e30f }, l_[2] = { 0.f, 0.f };

  const size_t kvb = (size_t)b * 2048 * 128;
  const int vd0 = (t & 7) * 8;
  const int vodd = (t >> 3) & 1;
  u16* Pw = &Ps[w][0];

  for (int jt = 0; jt < 16; ++jt) {
    __syncthreads();
    #pragma unroll
    for (int n = 0; n < 4; ++n) {
      const int cc = n * 256 + w * 64;
      const int ccl = cc + lane;
      const int row = ccl >> 3, lc = (ccl & 7) ^ (row & 7);
      GLDS16(&kv[kvb + (size_t)(jt * 128 + row) * 128 + lc * 8], Ks + (size_t)cc * 8);
    }
    #pragma unroll
    for (int c = 0; c < 4; ++c) {
      const int seg = c * 256 + t;
      const int vj = seg >> 3;
      const int jp = vj >> 1;
      const uint4 vv = *(const uint4*)&kv[kvb + (size_t)(jt * 128 + vj) * 128 + 64 + vd0];
      uint4 pvv;
      pvv.x = __shfl_xor((int)vv.x, 8);
      pvv.y = __shfl_xor((int)vv.y, 8);
      pvv.z = __shfl_xor((int)vv.z, 8);
      pvv.w = __shfl_xor((int)vv.w, 8);
      const unsigned ow[4] = { vv.x, vv.y, vv.z, vv.w };
      const unsigned pw[4] = { pvv.x, pvv.y, pvv.z, pvv.w };
      if (!vodd) {
        #pragma unroll
        for (int u = 0; u < 4; ++u) {
          const int d = vd0 + u;
          const unsigned own = (u & 1) ? (ow[u >> 1] >> 16) : (ow[u >> 1] & 0xffffu);
          const unsigned par = (u & 1) ? (pw[u >> 1] >> 16) : (pw[u >> 1] & 0xffffu);
          const int byteoff = d * 256 + ((4 * jp) ^ (((d & 7) ^ ((d >> 3) & 7)) << 4));
          *(unsigned*)((char*)Vt + byteoff) = own | (par << 16);
        }
      } else {
        #pragma unroll
        for (int u = 0; u < 4; ++u) {
          const int ue = u + 4;
          const int d = vd0 + ue;
          const unsigned own = (ue & 1) ? (ow[ue >> 1] >> 16) : (ow[ue >> 1] & 0xffffu);
          const unsigned par = (ue & 1) ? (pw[ue >> 1] >> 16) : (pw[ue >> 1] & 0xffffu);
          const int byteoff = d * 256 + ((4 * jp) ^ (((d & 7) ^ ((d >> 3) & 7)) << 4));
          *(unsigned*)((char*)Vt + byteoff) = par | (own << 16);
        }
      }
    }
    __syncthreads();

    #pragma unroll
    for (int t32 = 0; t32 < 2; ++t32) {
      f32x16 s[4];
      #pragma unroll
      for (int j32 = 0; j32 < 4; ++j32)
        #pragma unroll
        for (int r = 0; r < 16; ++r) s[j32][r] = 0.f;
      #pragma unroll
      for (int j32 = 0; j32 < 4; ++j32) {
        const int row = j32 * 32 + q32;
        #pragma unroll
        for (int dq = 0; dq < 4; ++dq) {
          const int slot = (dq * 2 + hl) ^ (row & 7);
          const short8 kf = *(const short8*)&Ks[row * 64 + slot * 8];
          s[j32] = __builtin_amdgcn_mfma_f32_32x32x16_bf16(kf, qa[t32][dq], s[j32], 0, 0, 0);
        }
      }
      float mt = -1e30f;
      #pragma unroll
      for (int j32 = 0; j32 < 4; ++j32)
        #pragma unroll
        for (int r = 0; r < 16; ++r) mt = fmaxf(mt, s[j32][r]);
      mt = fmaxf(mt, __shfl_xor(mt, 32));
      const float nm = fmaxf(m_[t32], mt);
      const float alpha = __expf(m_[t32] - nm);
      m_[t32] = nm;
      float lsum = 0.f;
      #pragma unroll
      for (int j32 = 0; j32 < 4; ++j32) {
        float p[16];
        #pragma unroll
        for (int r = 0; r < 16; ++r) { p[r] = __expf(s[j32][r] - nm); lsum += p[r]; }
        #pragma unroll
        for (int g = 0; g < 4; ++g) {
          const unsigned lo = cvtpk(p[4 * g + 0], p[4 * g + 1]);
          const unsigned hi = cvtpk(p[4 * g + 2], p[4 * g + 3]);
          const int j2 = j32 * 64 + 16 * g + 8 * hl;
          const int byteoff = q32 * 256 + (j2 ^ ((q32 & 7) << 4));
          uint2 wv; wv.x = lo; wv.y = hi;
          *(uint2*)((char*)Pw + byteoff) = wv;
        }
      }
      lsum += __shfl_xor(lsum, 32);
      l_[t32] = l_[t32] * alpha + lsum;
      #pragma unroll
      for (int d32 = 0; d32 < 2; ++d32)
        #pragma unroll
        for (int r = 0; r < 16; ++r) oacc[t32][d32][r] *= alpha;
      short8 pf[8];
      #pragma unroll
      for (int kk = 0; kk < 8; ++kk) {
        const int byteoff = q32 * 256 + ((kk * 32 + hl * 16) ^ ((q32 & 7) << 4));
        pf[kk] = *(const short8*)((const char*)Pw + byteoff);
      }
      #pragma unroll
      for (int d32 = 0; d32 < 2; ++d32) {
        const int dr = d32 * 32 + q32;
        const int vswz = ((dr & 7) ^ ((dr >> 3) & 7)) << 4;
        #pragma unroll
        for (int kk = 0; kk < 8; ++kk) {
          const int byteoff = dr * 256 + ((kk * 32 + hl * 16) ^ vswz);
          const short8 vf = *(const short8*)((const char*)Vt + byteoff);
          oacc[t32][d32] = __builtin_amdgcn_mfma_f32_32x32x16_bf16(vf, pf[kk], oacc[t32][d32], 0, 0, 0);
        }
      }
    }
  }

  float* Ot = (float*)Pw;
  #pragma unroll
  for (int t32 = 0; t32 < 2; ++t32) {
    const float inv = 1.0f / l_[t32];
    #pragma unroll
    for (int d32 = 0; d32 < 2; ++d32) {
      #pragma unroll
      for (int r = 0; r < 16; ++r) {
        const int d = (r & 3) + 8 * (r >> 2) + 4 * hl;
        const int byteoff = q32 * 128 + ((4 * d) ^ ((q32 & 7) << 4));
        *(float*)((char*)Ot + byteoff) = oacc[t32][d32][r] * inv;
      }
      const int qr = lane >> 1, dc = (lane & 1) * 16;
      union { u16 s[16]; uint4 v[2]; } ob;
      #pragma unroll
      for (int cch = 0; cch < 4; ++cch) {
        const int byteoff = qr * 128 + ((4 * (dc + 4 * cch)) ^ ((qr & 7) << 4));
        const f32x4 vv = *(const f32x4*)((const char*)Ot + byteoff);
        ob.s[cch * 4 + 0] = f2bf(vv[0]);
        ob.s[cch * 4 + 1] = f2bf(vv[1]);
        ob.s[cch * 4 + 2] = f2bf(vv[2]);
        ob.s[cch * 4 + 3] = f2bf(vv[3]);
      }
      u16* orow = &o[(qbase + t32 * 32 + qr) * 5120 + hd * 64 + d32 * 32 + dc];
      *(uint4*)orow = ob.v[0];
      *(uint4*)(orow + 8) = ob.v[1];
    }
  }
}

extern "C" void kernel_launch(void* const* d_in, const int* in_sizes, int n_in,
                              void* d_out, int out_size, void* d_ws, size_t ws_size,
                              hipStream_t stream)
{
  const float* x    = (const float*)d_in[0];
  const float* ctx  = (const float*)d_in[1];
  const float* ng   = (const float*)d_in[2];
  const float* nb   = (const float*)d_in[3];
  const float* cg   = (const float*)d_in[4];
  const float* cb   = (const float*)d_in[5];
  const float* Wq   = (const float*)d_in[6];
  const float* Wkv  = (const float*)d_in[7];
  const float* Wo   = (const float*)d_in[8];
  const float* Wff1 = (const float*)d_in[9];
  const float* Wff2 = (const float*)d_in[10];

  u16* p = (u16*)d_ws;
  u16* W1T   = p; p += (size_t)9216 * 1024;
  u16* WkvT  = p; p += (size_t)128 * 1024;
  u16* WcT   = p; p += (size_t)1024 * 5120;
  u16* kvbuf = p; p += (size_t)4096 * 128;
  u16* aoh   = p; p += (size_t)4096 * 5120;
  u16* xn    = p; p += (size_t)4096 * 1024;
  u16* cn    = p; p += (size_t)4096 * 1024;
  u16* qbuf  = p; p += (size_t)4096 * 1024;
  float* kvpart = (float*)W1T;                 // 16 MB over W1T (dead after qff GEMM)
  float* ffpart = (float*)xn;                  // 67 MB over xn|cn|qbuf + tail
  (void)in_sizes; (void)n_in; (void)out_size; (void)ws_size;

  ln_kernel<<<8192, 256, 0, stream>>>(x, ctx, ng, nb, cg, cb, xn, cn);

  transpose_k<<<dim3(16, 16),  256, 0, stream>>>(Wq,   W1T,        1024, 1024, 1024, 0.125f);
  transpose_ff1<<<dim3(128, 16), 256, 0, stream>>>(Wff1, W1T);
  transpose_k<<<dim3(2, 16),   256, 0, stream>>>(Wkv,  WkvT,       1024, 128,  1024, 1.0f);
  transpose_k<<<dim3(16, 16),  256, 0, stream>>>(Wo,   WcT,        1024, 1024, 5120, 1.0f);
  transpose_k<<<dim3(16, 64),  256, 0, stream>>>(Wff2, WcT + 1024, 4096, 1024, 5120, 1.0f);

  // fused: qbuf = xn@Wq*scale ; aoh[:,1024:] = silu(xn@Wff1); ORDER 0 (B-strip per XCD)
  gemm8p<2, 0><<<dim3(576), 512, 0, stream>>>(xn, W1T, qbuf, aoh, 4096, 9216, 1024, 1024);
  // kv = cn @ Wkv, split-K 8, reduce to bf16
  gemm_bt_sk<<<dim3(1, 32, 8), 256, 0, stream>>>(cn, WkvT, kvpart, 4096, 128, 128, 1024);
  reduce_kv<<<512, 256, 0, stream>>>(kvpart, kvbuf);
  // attention -> aoh[:,0:1024]
  attn_kernel<<<dim3(32, 4, 2), 256, 0, stream>>>(qbuf, kvbuf, aoh);
  // out = aoh @ [Wo ; Wff2]: 128^2 split-K 4 (1024 blocks = 4/CU), f32 partials, then reduce
  gemm_bt_sk<<<dim3(8, 32, 4), 256, 0, stream>>>(aoh, WcT, ffpart, 4096, 1024, 1280, 5120);
  reduce_out<<<4096, 256, 0, stream>>>(ffpart, (float*)d_out);
}

// Round 9
// 297.164 us; speedup vs baseline: 1.0922x; 1.0922x over previous
//
#include <hip/hip_runtime.h>
#include <stdint.h>

typedef unsigned short u16;
typedef __attribute__((ext_vector_type(8))) short short8;
typedef __attribute__((ext_vector_type(4))) float f32x4;
typedef __attribute__((ext_vector_type(16))) float f32x16;

#define GPTR(p) ((const __attribute__((address_space(1))) void*)(p))
#define SPTR(p) ((__attribute__((address_space(3))) void*)(p))
#define GLDS16(g, l) __builtin_amdgcn_global_load_lds(GPTR(g), SPTR(l), 16, 0, 0)

static __device__ __forceinline__ float bf2f(u16 u) {
  union { unsigned int i; float f; } c; c.i = ((unsigned int)u) << 16; return c.f;
}
static __device__ __forceinline__ u16 f2bf(float f) {
  union { float f; unsigned int u; } c; c.f = f;
  unsigned int r = 0x7fffu + ((c.u >> 16) & 1u);
  return (u16)((c.u + r) >> 16);
}
static __device__ __forceinline__ unsigned cvtpk(float a, float b) {
  unsigned r;
  asm volatile("v_cvt_pk_bf16_f32 %0, %1, %2" : "=v"(r) : "v"(a), "v"(b));
  return r;
}
static __device__ __forceinline__ int swz4(int row, int c) { return c ^ ((row >> 1) & 3); }

// ---------------- LayerNorm: f32 (rows of 1024) -> bf16 ----------------
__global__ __launch_bounds__(256) void ln_kernel(
    const float* __restrict__ x, const float* __restrict__ ctx,
    const float* __restrict__ g, const float* __restrict__ b,
    const float* __restrict__ cg, const float* __restrict__ cb,
    u16* __restrict__ xn, u16* __restrict__ cn)
{
  const int row = blockIdx.x;
  const float* src; const float* gg; const float* bb; u16* dst;
  if (row < 4096) { src = x + (size_t)row * 1024; gg = g;  bb = b;  dst = xn + (size_t)row * 1024; }
  else            { src = ctx + (size_t)(row - 4096) * 1024; gg = cg; bb = cb; dst = cn + (size_t)(row - 4096) * 1024; }
  const int t = threadIdx.x;
  float4 v = *(const float4*)&src[t * 4];
  float s  = v.x + v.y + v.z + v.w;
  float s2 = v.x * v.x + v.y * v.y + v.z * v.z + v.w * v.w;
  #pragma unroll
  for (int off = 1; off < 64; off <<= 1) { s += __shfl_xor(s, off); s2 += __shfl_xor(s2, off); }
  __shared__ float ls[4], ls2[4];
  const int w = t >> 6;
  if ((t & 63) == 0) { ls[w] = s; ls2[w] = s2; }
  __syncthreads();
  s  = ls[0] + ls[1] + ls[2] + ls[3];
  s2 = ls2[0] + ls2[1] + ls2[2] + ls2[3];
  const float mu   = s * (1.0f / 1024.0f);
  const float var  = s2 * (1.0f / 1024.0f) - mu * mu;
  const float rstd = rsqrtf(var + 1e-5f);
  float xv[4] = { v.x, v.y, v.z, v.w };
  u16 o[4];
  #pragma unroll
  for (int i = 0; i < 4; ++i)
    o[i] = f2bf((xv[i] - mu) * rstd * gg[t * 4 + i] + bb[t * 4 + i]);
  uint2 pv;
  pv.x = (unsigned)o[0] | ((unsigned)o[1] << 16);
  pv.y = (unsigned)o[2] | ((unsigned)o[3] << 16);
  *(uint2*)&dst[t * 4] = pv;
}

// ---------------- transpose+convert: f32 (R,C) -> bf16 (C,R) with out leading dim ----------------
__global__ __launch_bounds__(256) void transpose_k(
    const float* __restrict__ in, u16* __restrict__ out, int R, int C, int ldo, float scale)
{
  __shared__ float tile[64][65];
  const int c0 = blockIdx.x * 64, r0 = blockIdx.y * 64;
  const int t = threadIdx.x;
  const int tr = t >> 4, tc = (t & 15) * 4;
  #pragma unroll
  for (int i = 0; i < 4; ++i) {
    int r = tr + i * 16;
    float4 v = *(const float4*)&in[(size_t)(r0 + r) * C + c0 + tc];
    tile[r][tc + 0] = v.x; tile[r][tc + 1] = v.y; tile[r][tc + 2] = v.z; tile[r][tc + 3] = v.w;
  }
  __syncthreads();
  #pragma unroll
  for (int i = 0; i < 2; ++i) {
    int c  = (t >> 3) + i * 32;
    int rb = (t & 7) * 8;
    union { u16 s[8]; uint4 v; } pk;
    #pragma unroll
    for (int u = 0; u < 8; ++u) pk.s[u] = f2bf(tile[rb + u][c] * scale);
    *(uint4*)&out[(size_t)(c0 + c) * ldo + r0 + rb] = pk.v;
  }
}

// ---------------- Wff1 transpose with (a,gate) fragment interleave ----------------
__global__ __launch_bounds__(256) void transpose_ff1(
    const float* __restrict__ in, u16* __restrict__ out)
{
  __shared__ float tile[64][65];
  const int c0 = blockIdx.x * 64, r0 = blockIdx.y * 64;
  const int t = threadIdx.x;
  const int tr = t >> 4, tc = (t & 15) * 4;
  #pragma unroll
  for (int i = 0; i < 4; ++i) {
    int r = tr + i * 16;
    float4 v = *(const float4*)&in[(size_t)(r0 + r) * 8192 + c0 + tc];
    tile[r][tc + 0] = v.x; tile[r][tc + 1] = v.y; tile[r][tc + 2] = v.z; tile[r][tc + 3] = v.w;
  }
  __syncthreads();
  #pragma unroll
  for (int i = 0; i < 2; ++i) {
    int c  = (t >> 3) + i * 32;
    int rb = (t & 7) * 8;
    const int gc = c0 + c;
    int j, add16;
    if (gc < 4096) { j = gc; add16 = 0; } else { j = gc - 4096; add16 = 16; }
    const int row = 1024 + ((j >> 7) << 8) + (((j >> 5) & 3) << 6) + (((j >> 4) & 1) << 5) + add16 + (j & 15);
    union { u16 s[8]; uint4 v; } pk;
    #pragma unroll
    for (int u = 0; u < 8; ++u) pk.s[u] = f2bf(tile[rb + u][c]);
    *(uint4*)&out[(size_t)row * 1024 + r0 + rb] = pk.v;
  }
}

// =============== 8-phase 256x256 GEMM (BK=64, 8 waves, 2-deep dbuf) ===============
#define MM1(MQ, M, NN, BF) acc[MQ][M][NN] = __builtin_amdgcn_mfma_f32_16x16x32_bf16(af##M, BF, acc[MQ][M][NN], 0, 0, 0)
#define MFMA16(MQ, KS) \
  MM1(MQ,0,0,bf##KS##0); MM1(MQ,0,1,bf##KS##1); MM1(MQ,0,2,bf##KS##2); MM1(MQ,0,3,bf##KS##3); \
  MM1(MQ,1,0,bf##KS##0); MM1(MQ,1,1,bf##KS##1); MM1(MQ,1,2,bf##KS##2); MM1(MQ,1,3,bf##KS##3); \
  MM1(MQ,2,0,bf##KS##0); MM1(MQ,2,1,bf##KS##1); MM1(MQ,2,2,bf##KS##2); MM1(MQ,2,3,bf##KS##3); \
  MM1(MQ,3,0,bf##KS##0); MM1(MQ,3,1,bf##KS##1); MM1(MQ,3,2,bf##KS##2); MM1(MQ,3,3,bf##KS##3)

#define SG_A(SBUF, H, KT) do { \
    GLDS16(gA[H][0] + ((size_t)(KT) << 6), SBUF + ((H) * 64 + w16o) * 64); \
    GLDS16(gA[H][1] + ((size_t)(KT) << 6), SBUF + ((H) * 64 + w16o + 8) * 64); \
  } while (0)
#define SG_B(SBUF, H, KT) do { \
    GLDS16(gB[H][0] + ((size_t)(KT) << 6), SBUF + ((H) * 128 + w16o2) * 64); \
    GLDS16(gB[H][1] + ((size_t)(KT) << 6), SBUF + ((H) * 128 + w16o2 + 8) * 64); \
  } while (0)

#define DS_B(PB_) do { \
  bf00 = *(const short8*)(PB_ + 0    + cks0); bf01 = *(const short8*)(PB_ + 1024 + cks0); \
  bf02 = *(const short8*)(PB_ + 2048 + cks0); bf03 = *(const short8*)(PB_ + 3072 + cks0); \
  bf10 = *(const short8*)(PB_ + 0    + cks1); bf11 = *(const short8*)(PB_ + 1024 + cks1); \
  bf12 = *(const short8*)(PB_ + 2048 + cks1); bf13 = *(const short8*)(PB_ + 3072 + cks1); \
} while (0)

#define P_CORE(PA_, MQ, KS, STAGE_STMT, PREB_STMT, GATE_STMT) do { \
  af0 = *(const short8*)(PA_ + (MQ) * 4096 + 0    + cks##KS); \
  af1 = *(const short8*)(PA_ + (MQ) * 4096 + 1024 + cks##KS); \
  af2 = *(const short8*)(PA_ + (MQ) * 4096 + 2048 + cks##KS); \
  af3 = *(const short8*)(PA_ + (MQ) * 4096 + 3072 + cks##KS); \
  STAGE_STMT; \
  PREB_STMT; \
  __builtin_amdgcn_s_barrier(); \
  asm volatile("s_waitcnt lgkmcnt(0)" ::: "memory"); \
  __builtin_amdgcn_s_setprio(1); \
  MFMA16(MQ, KS); \
  __builtin_amdgcn_s_setprio(0); \
  GATE_STMT; \
  __builtin_amdgcn_s_barrier(); \
} while (0)

#define GATE6 asm volatile("s_waitcnt vmcnt(6)" ::: "memory")
#define GATE0 asm volatile("s_waitcnt vmcnt(0)" ::: "memory")
#define HINT8 asm volatile("s_waitcnt lgkmcnt(8)" ::: "memory")

template<int MODE, int ORDER>
__global__ __launch_bounds__(512, 2) void gemm8p(
    const u16* __restrict__ A, const u16* __restrict__ BT, void* __restrict__ C,
    void* __restrict__ C2, int M, int N, int Ktot, int Kslice)
{
  __shared__ u16 sh[2][2][16384]; // [buf][A/B][256*64]
  const int nbn = N >> 8, nbm = M >> 8;
  const int nwg = gridDim.x;
  const int bid = blockIdx.x;
  const int o = (bid & 7) * (nwg >> 3) + (bid >> 3);  // chunked bijective XCD map (nwg%8==0)
  int bm, bn;
  if constexpr (ORDER == 0) { bm = o % nbm; bn = o / nbm; }  // B-strip per XCD
  else                      { bn = o % nbn; bm = o / nbn; }  // A-panels per XCD
  const int kbase = blockIdx.y * Kslice;
  const int NI = Kslice >> 7;

  const int t = threadIdx.x, w = t >> 6, lane = t & 63;
  const int wr = w >> 2, wc = w & 3;
  const int lr = lane & 15, lg = lane >> 4;
  const int r8 = lane >> 3, ch = lane & 7;
  const int clog = ch ^ r8;
  const int w16o  = w * 16 + ((w >= 4) ? 64 : 0);
  const int w16o2 = w * 16;

  const u16* gA[2][2]; const u16* gB[2][2];
  #pragma unroll
  for (int h = 0; h < 2; ++h)
    #pragma unroll
    for (int qq = 0; qq < 2; ++qq) {
      gA[h][qq] = A  + (size_t)(bm * 256 + h * 64  + w16o  + qq * 8 + r8) * Ktot + kbase + clog * 8;
      gB[h][qq] = BT + (size_t)(bn * 256 + h * 128 + w16o2 + qq * 8 + r8) * Ktot + kbase + clog * 8;
    }
  u16* sA0 = &sh[0][0][0]; u16* sA1 = &sh[1][0][0];
  u16* sB0 = &sh[0][1][0]; u16* sB1 = &sh[1][1][0];
  const int cks0 = ((0 + lg) ^ (lr & 7)) * 8;
  const int cks1 = ((4 + lg) ^ (lr & 7)) * 8;
  const u16* pA_b0 = sA0 + (wr * 128 + lr) * 64;
  const u16* pA_b1 = sA1 + (wr * 128 + lr) * 64;
  const u16* pB_b0 = sB0 + (wc * 64 + lr) * 64;
  const u16* pB_b1 = sB1 + (wc * 64 + lr) * 64;

  f32x4 acc[2][4][4];
  const f32x4 z4 = { 0.f, 0.f, 0.f, 0.f };
  #pragma unroll
  for (int a = 0; a < 2; ++a)
    #pragma unroll
    for (int b = 0; b < 4; ++b)
      #pragma unroll
      for (int c = 0; c < 4; ++c) acc[a][b][c] = z4;
  short8 af0, af1, af2, af3;
  short8 bf00, bf01, bf02, bf03, bf10, bf11, bf12, bf13;

  SG_B(sB0, 0, 0); SG_B(sB0, 1, 0); SG_A(sA0, 0, 0); SG_A(sA0, 1, 0);
  SG_B(sB1, 0, 1); SG_B(sB1, 1, 1); SG_A(sA1, 0, 1);
  GATE6;
  __builtin_amdgcn_s_barrier();

  for (int i = 0; i < NI; ++i) {
    const int k2 = 2 * i;
    const bool st = (i < NI - 1);
    DS_B(pB_b0);
    P_CORE(pA_b0, 0, 0, SG_A(sA1, 1, k2 + 1), HINT8, );
    P_CORE(pA_b0, 1, 0, if (st) SG_B(sB0, 0, k2 + 2), , );
    P_CORE(pA_b0, 0, 1, if (st) SG_B(sB0, 1, k2 + 2), , );
    P_CORE(pA_b0, 1, 1, if (st) SG_A(sA0, 0, k2 + 2), ,
           if (st) { GATE6; } else { GATE0; });
    DS_B(pB_b1);
    P_CORE(pA_b1, 0, 0, if (st) SG_A(sA0, 1, k2 + 2), HINT8, );
    P_CORE(pA_b1, 1, 0, if (st) SG_B(sB1, 0, k2 + 3), , );
    P_CORE(pA_b1, 0, 1, if (st) SG_B(sB1, 1, k2 + 3), , );
    P_CORE(pA_b1, 1, 1, if (st) SG_A(sA1, 0, k2 + 3), ,
           if (st) { GATE6; });
  }

  if constexpr (MODE == 1) {
    float* Co = (float*)C + (size_t)blockIdx.y * M * N;
    #pragma unroll
    for (int mq = 0; mq < 2; ++mq)
      #pragma unroll
      for (int m = 0; m < 4; ++m)
        #pragma unroll
        for (int n = 0; n < 4; ++n)
          #pragma unroll
          for (int rr = 0; rr < 4; ++rr) {
            const int row = bm * 256 + wr * 128 + mq * 64 + m * 16 + lg * 4 + rr;
            const int col = bn * 256 + wc * 64 + n * 16 + lr;
            Co[(size_t)row * N + col] = acc[mq][m][n][rr];
          }
  } else {
    if (bn < 4) {
      u16* Co = (u16*)C; // qbuf, stride 1024
      #pragma unroll
      for (int mq = 0; mq < 2; ++mq)
        #pragma unroll
        for (int m = 0; m < 4; ++m)
          #pragma unroll
          for (int n = 0; n < 4; ++n)
            #pragma unroll
            for (int rr = 0; rr < 4; ++rr) {
              const int row = bm * 256 + wr * 128 + mq * 64 + m * 16 + lg * 4 + rr;
              const int col = bn * 256 + wc * 64 + n * 16 + lr;
              Co[(size_t)row * 1024 + col] = f2bf(acc[mq][m][n][rr]);
            }
    } else {
      u16* Ho = (u16*)C2; // aoh, stride 5120, h starts at col 1024
      const int colb = 1024 + (bn - 4) * 128 + wc * 32 + lr;
      #pragma unroll
      for (int mq = 0; mq < 2; ++mq)
        #pragma unroll
        for (int m = 0; m < 4; ++m)
          #pragma unroll
          for (int rr = 0; rr < 4; ++rr) {
            const int row = bm * 256 + wr * 128 + mq * 64 + m * 16 + lg * 4 + rr;
            #pragma unroll
            for (int n2 = 0; n2 < 2; ++n2) {
              const float a = acc[mq][m][2 * n2][rr];
              const float gt = acc[mq][m][2 * n2 + 1][rr];
              const float h = a * gt / (1.0f + __expf(-gt));
              Ho[(size_t)row * 5120 + colb + n2 * 16] = f2bf(h);
            }
          }
    }
  }
}

// ---------------- split-K GEMM 128x128 (tiny kv projection) ----------------
__global__ __launch_bounds__(256) void gemm_bt_sk(
    const u16* __restrict__ A, const u16* __restrict__ BT, float* __restrict__ Cp,
    int M, int N, int Kslice, int Ktot)
{
  __shared__ u16 As[128 * 32];
  __shared__ u16 Bs[128 * 32];
  const int bm = blockIdx.y, bn = blockIdx.x, z = blockIdx.z;
  const int t = threadIdx.x;
  const int w = t >> 6, lane = t & 63;
  const int wr = w >> 1, wc = w & 1;
  const int lr = lane & 15, lkc = lane >> 4;

  f32x4 acc[4][4];
  const f32x4 z4 = { 0.f, 0.f, 0.f, 0.f };
  #pragma unroll
  for (int mi = 0; mi < 4; ++mi)
    #pragma unroll
    for (int ni = 0; ni < 4; ++ni) acc[mi][ni] = z4;

  const int kbase = z * Kslice;
  const int i0 = t, i1 = t + 256;
  const int r0 = i0 >> 2, k0 = swz4(r0, i0 & 3) * 8;
  const int r1 = i1 >> 2, k1 = swz4(r1, i1 & 3) * 8;
  const u16* a0 = A + (size_t)(bm * 128 + r0) * Ktot + kbase + k0;
  const u16* a1 = A + (size_t)(bm * 128 + r1) * Ktot + kbase + k1;
  const u16* b0 = BT + (size_t)(bn * 128 + r0) * Ktot + kbase + k0;
  const u16* b1 = BT + (size_t)(bn * 128 + r1) * Ktot + kbase + k1;
  u16* As0 = As + (size_t)w * 512;
  u16* As1 = As + (size_t)(w + 4) * 512;
  u16* Bs0 = Bs + (size_t)w * 512;
  u16* Bs1 = Bs + (size_t)(w + 4) * 512;

  const int nk = Kslice >> 5;
  for (int kt = 0; kt < nk; ++kt) {
    __syncthreads();
    GLDS16(a0, As0); GLDS16(a1, As1); GLDS16(b0, Bs0); GLDS16(b1, Bs1);
    a0 += 32; a1 += 32; b0 += 32; b1 += 32;
    __syncthreads();
    short8 af[4], bf[4];
    #pragma unroll
    for (int mi = 0; mi < 4; ++mi) {
      int row = wr * 64 + mi * 16 + lr;
      af[mi] = *(const short8*)&As[row * 32 + swz4(row, lkc) * 8];
    }
    #pragma unroll
    for (int ni = 0; ni < 4; ++ni) {
      int row = wc * 64 + ni * 16 + lr;
      bf[ni] = *(const short8*)&Bs[row * 32 + swz4(row, lkc) * 8];
    }
    #pragma unroll
    for (int mi = 0; mi < 4; ++mi)
      #pragma unroll
      for (int ni = 0; ni < 4; ++ni)
        acc[mi][ni] = __builtin_amdgcn_mfma_f32_16x16x32_bf16(af[mi], bf[ni], acc[mi][ni], 0, 0, 0);
  }

  float* Cz = Cp + (size_t)z * M * N;
  const int row0 = bm * 128 + wr * 64, col0 = bn * 128 + wc * 64;
  const int rsub = (lane >> 4) * 4;
  #pragma unroll
  for (int mi = 0; mi < 4; ++mi)
    #pragma unroll
    for (int ni = 0; ni < 4; ++ni)
      #pragma unroll
      for (int r = 0; r < 4; ++r)
        Cz[(size_t)(row0 + mi * 16 + rsub + r) * N + (col0 + ni * 16 + lr)] = acc[mi][ni][r];
}

// ---------------- reduce 8 f32 partials (4096x128) -> bf16 ----------------
__global__ __launch_bounds__(256) void reduce_kv(const float* __restrict__ part, u16* __restrict__ out)
{
  const size_t base = ((size_t)blockIdx.x * 256 + threadIdx.x) * 4;
  f32x4 s = *(const f32x4*)&part[base];
  #pragma unroll
  for (int zz = 1; zz < 8; ++zz) {
    const f32x4 v = *(const f32x4*)&part[(size_t)zz * 524288 + base];
    s[0] += v[0]; s[1] += v[1]; s[2] += v[2]; s[3] += v[3];
  }
  uint2 pv;
  pv.x = (unsigned)f2bf(s[0]) | ((unsigned)f2bf(s[1]) << 16);
  pv.y = (unsigned)f2bf(s[2]) | ((unsigned)f2bf(s[3]) << 16);
  *(uint2*)&out[base] = pv;
}

// ---------------- out = sum of 4 f32 partials (4096x1024) ----------------
__global__ __launch_bounds__(256) void reduce_out(const float* __restrict__ part, float* __restrict__ out)
{
  const size_t base = ((size_t)blockIdx.x * 256 + threadIdx.x) * 4;
  f32x4 s = *(const f32x4*)&part[base];
  #pragma unroll
  for (int zz = 1; zz < 4; ++zz) {
    const f32x4 v = *(const f32x4*)&part[(size_t)zz * 4194304 + base];
    s[0] += v[0]; s[1] += v[1]; s[2] += v[2]; s[3] += v[3];
  }
  *(f32x4*)&out[base] = s;
}

// ---------------- flash cross-attention (multi-query: 1 KV head) ----------------
// 64 q-rows per wave (2 q32 tiles), 4 heads/block, grid (N/64, H/4, B) = 256 blocks.
// T13 defer-max: skip max-update + O-rescale when tile max <= m + 8 (wave-uniform).
__global__ __launch_bounds__(256) void attn_kernel(
    const u16* __restrict__ q, const u16* __restrict__ kv, u16* __restrict__ o)
{
  __shared__ u16 Ks[128 * 64];
  __shared__ u16 Vt[64 * 128];
  __shared__ u16 Ps[4][32 * 128];
  const int b = blockIdx.z, hb = blockIdx.y, qb = blockIdx.x;
  const int t = threadIdx.x, w = t >> 6, lane = t & 63;
  const int q32 = lane & 31, hl = lane >> 5;
  const int hd = hb * 4 + w;

  const size_t qbase = (size_t)b * 2048 + qb * 64;
  short8 qa[2][4];
  #pragma unroll
  for (int t32 = 0; t32 < 2; ++t32)
    #pragma unroll
    for (int dq = 0; dq < 4; ++dq)
      qa[t32][dq] = *(const short8*)&q[(qbase + t32 * 32 + q32) * 1024 + hd * 64 + dq * 16 + hl * 8];

  f32x16 oacc[2][2];
  #pragma unroll
  for (int i = 0; i < 2; ++i)
    #pragma unroll
    for (int j = 0; j < 2; ++j)
      #pragma unroll
      for (int r = 0; r < 16; ++r) oacc[i][j][r] = 0.f;
  float m_[2] = { -1e30f, -1e30f }, l_[2] = { 0.f, 0.f };

  const size_t kvb = (size_t)b * 2048 * 128;
  const int vd0 = (t & 7) * 8;
  const int vodd = (t >> 3) & 1;
  u16* Pw = &Ps[w][0];

  for (int jt = 0; jt < 16; ++jt) {
    __syncthreads();
    #pragma unroll
    for (int n = 0; n < 4; ++n) {
      const int cc = n * 256 + w * 64;
      const int ccl = cc + lane;
      const int row = ccl >> 3, lc = (ccl & 7) ^ (row & 7);
      GLDS16(&kv[kvb + (size_t)(jt * 128 + row) * 128 + lc * 8], Ks + (size_t)cc * 8);
    }
    #pragma unroll
    for (int c = 0; c < 4; ++c) {
      const int seg = c * 256 + t;
      const int vj = seg >> 3;
      const int jp = vj >> 1;
      const uint4 vv = *(const uint4*)&kv[kvb + (size_t)(jt * 128 + vj) * 128 + 64 + vd0];
      uint4 pvv;
      pvv.x = __shfl_xor((int)vv.x, 8);
      pvv.y = __shfl_xor((int)vv.y, 8);
      pvv.z = __shfl_xor((int)vv.z, 8);
      pvv.w = __shfl_xor((int)vv.w, 8);
      const unsigned ow[4] = { vv.x, vv.y, vv.z, vv.w };
      const unsigned pw[4] = { pvv.x, pvv.y, pvv.z, pvv.w };
      if (!vodd) {
        #pragma unroll
        for (int u = 0; u < 4; ++u) {
          const int d = vd0 + u;
          const unsigned own = (u & 1) ? (ow[u >> 1] >> 16) : (ow[u >> 1] & 0xffffu);
          const unsigned par = (u & 1) ? (pw[u >> 1] >> 16) : (pw[u >> 1] & 0xffffu);
          const int byteoff = d * 256 + ((4 * jp) ^ (((d & 7) ^ ((d >> 3) & 7)) << 4));
          *(unsigned*)((char*)Vt + byteoff) = own | (par << 16);
        }
      } else {
        #pragma unroll
        for (int u = 0; u < 4; ++u) {
          const int ue = u + 4;
          const int d = vd0 + ue;
          const unsigned own = (ue & 1) ? (ow[ue >> 1] >> 16) : (ow[ue >> 1] & 0xffffu);
          const unsigned par = (ue & 1) ? (pw[ue >> 1] >> 16) : (pw[ue >> 1] & 0xffffu);
          const int byteoff = d * 256 + ((4 * jp) ^ (((d & 7) ^ ((d >> 3) & 7)) << 4));
          *(unsigned*)((char*)Vt + byteoff) = par | (own << 16);
        }
      }
    }
    __syncthreads();

    #pragma unroll
    for (int t32 = 0; t32 < 2; ++t32) {
      f32x16 s[4];
      #pragma unroll
      for (int j32 = 0; j32 < 4; ++j32)
        #pragma unroll
        for (int r = 0; r < 16; ++r) s[j32][r] = 0.f;
      #pragma unroll
      for (int j32 = 0; j32 < 4; ++j32) {
        const int row = j32 * 32 + q32;
        #pragma unroll
        for (int dq = 0; dq < 4; ++dq) {
          const int slot = (dq * 2 + hl) ^ (row & 7);
          const short8 kf = *(const short8*)&Ks[row * 64 + slot * 8];
          s[j32] = __builtin_amdgcn_mfma_f32_32x32x16_bf16(kf, qa[t32][dq], s[j32], 0, 0, 0);
        }
      }
      float mt = -1e30f;
      #pragma unroll
      for (int j32 = 0; j32 < 4; ++j32)
        #pragma unroll
        for (int r = 0; r < 16; ++r) mt = fmaxf(mt, s[j32][r]);
      mt = fmaxf(mt, __shfl_xor(mt, 32));
      // T13 defer-max: if no row grew past m+8, keep old max (skip alpha & O-rescale)
      const bool noresc = (bool)__all(mt <= m_[t32] + 8.0f);
      float nm = m_[t32];
      if (!noresc) {
        nm = fmaxf(m_[t32], mt);
        const float alpha = __expf(m_[t32] - nm);
        m_[t32] = nm;
        l_[t32] *= alpha;
        #pragma unroll
        for (int d32 = 0; d32 < 2; ++d32)
          #pragma unroll
          for (int r = 0; r < 16; ++r) oacc[t32][d32][r] *= alpha;
      }
      float lsum = 0.f;
      #pragma unroll
      for (int j32 = 0; j32 < 4; ++j32) {
        float p[16];
        #pragma unroll
        for (int r = 0; r < 16; ++r) { p[r] = __expf(s[j32][r] - nm); lsum += p[r]; }
        #pragma unroll
        for (int g = 0; g < 4; ++g) {
          const unsigned lo = cvtpk(p[4 * g + 0], p[4 * g + 1]);
          const unsigned hi = cvtpk(p[4 * g + 2], p[4 * g + 3]);
          const int j2 = j32 * 64 + 16 * g + 8 * hl;
          const int byteoff = q32 * 256 + (j2 ^ ((q32 & 7) << 4));
          uint2 wv; wv.x = lo; wv.y = hi;
          *(uint2*)((char*)Pw + byteoff) = wv;
        }
      }
      lsum += __shfl_xor(lsum, 32);
      l_[t32] += lsum;
      short8 pf[8];
      #pragma unroll
      for (int kk = 0; kk < 8; ++kk) {
        const int byteoff = q32 * 256 + ((kk * 32 + hl * 16) ^ ((q32 & 7) << 4));
        pf[kk] = *(const short8*)((const char*)Pw + byteoff);
      }
      #pragma unroll
      for (int d32 = 0; d32 < 2; ++d32) {
        const int dr = d32 * 32 + q32;
        const int vswz = ((dr & 7) ^ ((dr >> 3) & 7)) << 4;
        #pragma unroll
        for (int kk = 0; kk < 8; ++kk) {
          const int byteoff = dr * 256 + ((kk * 32 + hl * 16) ^ vswz);
          const short8 vf = *(const short8*)((const char*)Vt + byteoff);
          oacc[t32][d32] = __builtin_amdgcn_mfma_f32_32x32x16_bf16(vf, pf[kk], oacc[t32][d32], 0, 0, 0);
        }
      }
    }
  }

  float* Ot = (float*)Pw;
  #pragma unroll
  for (int t32 = 0; t32 < 2; ++t32) {
    const float inv = 1.0f / l_[t32];
    #pragma unroll
    for (int d32 = 0; d32 < 2; ++d32) {
      #pragma unroll
      for (int r = 0; r < 16; ++r) {
        const int d = (r & 3) + 8 * (r >> 2) + 4 * hl;
        const int byteoff = q32 * 128 + ((4 * d) ^ ((q32 & 7) << 4));
        *(float*)((char*)Ot + byteoff) = oacc[t32][d32][r] * inv;
      }
      const int qr = lane >> 1, dc = (lane & 1) * 16;
      union { u16 s[16]; uint4 v[2]; } ob;
      #pragma unroll
      for (int cch = 0; cch < 4; ++cch) {
        const int byteoff = qr * 128 + ((4 * (dc + 4 * cch)) ^ ((qr & 7) << 4));
        const f32x4 vv = *(const f32x4*)((const char*)Ot + byteoff);
        ob.s[cch * 4 + 0] = f2bf(vv[0]);
        ob.s[cch * 4 + 1] = f2bf(vv[1]);
        ob.s[cch * 4 + 2] = f2bf(vv[2]);
        ob.s[cch * 4 + 3] = f2bf(vv[3]);
      }
      u16* orow = &o[(qbase + t32 * 32 + qr) * 5120 + hd * 64 + d32 * 32 + dc];
      *(uint4*)orow = ob.v[0];
      *(uint4*)(orow + 8) = ob.v[1];
    }
  }
}

extern "C" void kernel_launch(void* const* d_in, const int* in_sizes, int n_in,
                              void* d_out, int out_size, void* d_ws, size_t ws_size,
                              hipStream_t stream)
{
  const float* x    = (const float*)d_in[0];
  const float* ctx  = (const float*)d_in[1];
  const float* ng   = (const float*)d_in[2];
  const float* nb   = (const float*)d_in[3];
  const float* cg   = (const float*)d_in[4];
  const float* cb   = (const float*)d_in[5];
  const float* Wq   = (const float*)d_in[6];
  const float* Wkv  = (const float*)d_in[7];
  const float* Wo   = (const float*)d_in[8];
  const float* Wff1 = (const float*)d_in[9];
  const float* Wff2 = (const float*)d_in[10];

  u16* p = (u16*)d_ws;
  u16* W1T   = p; p += (size_t)9216 * 1024;
  u16* WkvT  = p; p += (size_t)128 * 1024;
  u16* WcT   = p; p += (size_t)1024 * 5120;
  u16* kvbuf = p; p += (size_t)4096 * 128;
  u16* aoh   = p; p += (size_t)4096 * 5120;
  u16* xn    = p; p += (size_t)4096 * 1024;
  u16* cn    = p; p += (size_t)4096 * 1024;
  u16* qbuf  = p; p += (size_t)4096 * 1024;
  float* kvpart = (float*)W1T;                 // 16 MB over W1T (dead after qff GEMM)
  float* ffpart = (float*)xn;                  // 64 MB over xn|cn|qbuf + tail
  (void)in_sizes; (void)n_in; (void)out_size; (void)ws_size;

  ln_kernel<<<8192, 256, 0, stream>>>(x, ctx, ng, nb, cg, cb, xn, cn);

  transpose_k<<<dim3(16, 16),  256, 0, stream>>>(Wq,   W1T,        1024, 1024, 1024, 0.125f);
  transpose_ff1<<<dim3(128, 16), 256, 0, stream>>>(Wff1, W1T);
  transpose_k<<<dim3(2, 16),   256, 0, stream>>>(Wkv,  WkvT,       1024, 128,  1024, 1.0f);
  transpose_k<<<dim3(16, 16),  256, 0, stream>>>(Wo,   WcT,        1024, 1024, 5120, 1.0f);
  transpose_k<<<dim3(16, 64),  256, 0, stream>>>(Wff2, WcT + 1024, 4096, 1024, 5120, 1.0f);

  // fused: qbuf = xn@Wq*scale ; aoh[:,1024:] = silu(xn@Wff1); ORDER 0 (B-strip per XCD)
  gemm8p<2, 0><<<dim3(576), 512, 0, stream>>>(xn, W1T, qbuf, aoh, 4096, 9216, 1024, 1024);
  // kv = cn @ Wkv, split-K 8, reduce to bf16
  gemm_bt_sk<<<dim3(1, 32, 8), 256, 0, stream>>>(cn, WkvT, kvpart, 4096, 128, 128, 1024);
  reduce_kv<<<512, 256, 0, stream>>>(kvpart, kvbuf);
  // attention -> aoh[:,0:1024]
  attn_kernel<<<dim3(32, 4, 2), 256, 0, stream>>>(qbuf, kvbuf, aoh);
  // out = aoh @ [Wo ; Wff2], split-K 4; ORDER 1 (A-panels per XCD), 8-phase
  gemm8p<1, 1><<<dim3(64, 4), 512, 0, stream>>>(aoh, WcT, ffpart, nullptr, 4096, 1024, 5120, 1280);
  reduce_out<<<4096, 256, 0, stream>>>(ffpart, (float*)d_out);
}

// Round 10
// 287.474 us; speedup vs baseline: 1.1290x; 1.0337x over previous
//
#include <hip/hip_runtime.h>
#include <stdint.h>

typedef unsigned short u16;
typedef __attribute__((ext_vector_type(8))) short short8;
typedef __attribute__((ext_vector_type(4))) float f32x4;
typedef __attribute__((ext_vector_type(16))) float f32x16;

#define GPTR(p) ((const __attribute__((address_space(1))) void*)(p))
#define SPTR(p) ((__attribute__((address_space(3))) void*)(p))
#define GLDS16(g, l) __builtin_amdgcn_global_load_lds(GPTR(g), SPTR(l), 16, 0, 0)

static __device__ __forceinline__ float bf2f(u16 u) {
  union { unsigned int i; float f; } c; c.i = ((unsigned int)u) << 16; return c.f;
}
static __device__ __forceinline__ u16 f2bf(float f) {
  union { float f; unsigned int u; } c; c.f = f;
  unsigned int r = 0x7fffu + ((c.u >> 16) & 1u);
  return (u16)((c.u + r) >> 16);
}
static __device__ __forceinline__ unsigned cvtpk(float a, float b) {
  unsigned r;
  asm volatile("v_cvt_pk_bf16_f32 %0, %1, %2" : "=v"(r) : "v"(a), "v"(b));
  return r;
}
static __device__ __forceinline__ int swz4(int row, int c) { return c ^ ((row >> 1) & 3); }

// ---------------- LayerNorm: f32 (rows of 1024) -> bf16 ----------------
__global__ __launch_bounds__(256) void ln_kernel(
    const float* __restrict__ x, const float* __restrict__ ctx,
    const float* __restrict__ g, const float* __restrict__ b,
    const float* __restrict__ cg, const float* __restrict__ cb,
    u16* __restrict__ xn, u16* __restrict__ cn)
{
  const int row = blockIdx.x;
  const float* src; const float* gg; const float* bb; u16* dst;
  if (row < 4096) { src = x + (size_t)row * 1024; gg = g;  bb = b;  dst = xn + (size_t)row * 1024; }
  else            { src = ctx + (size_t)(row - 4096) * 1024; gg = cg; bb = cb; dst = cn + (size_t)(row - 4096) * 1024; }
  const int t = threadIdx.x;
  float4 v = *(const float4*)&src[t * 4];
  float s  = v.x + v.y + v.z + v.w;
  float s2 = v.x * v.x + v.y * v.y + v.z * v.z + v.w * v.w;
  #pragma unroll
  for (int off = 1; off < 64; off <<= 1) { s += __shfl_xor(s, off); s2 += __shfl_xor(s2, off); }
  __shared__ float ls[4], ls2[4];
  const int w = t >> 6;
  if ((t & 63) == 0) { ls[w] = s; ls2[w] = s2; }
  __syncthreads();
  s  = ls[0] + ls[1] + ls[2] + ls[3];
  s2 = ls2[0] + ls2[1] + ls2[2] + ls2[3];
  const float mu   = s * (1.0f / 1024.0f);
  const float var  = s2 * (1.0f / 1024.0f) - mu * mu;
  const float rstd = rsqrtf(var + 1e-5f);
  float xv[4] = { v.x, v.y, v.z, v.w };
  u16 o[4];
  #pragma unroll
  for (int i = 0; i < 4; ++i)
    o[i] = f2bf((xv[i] - mu) * rstd * gg[t * 4 + i] + bb[t * 4 + i]);
  uint2 pv;
  pv.x = (unsigned)o[0] | ((unsigned)o[1] << 16);
  pv.y = (unsigned)o[2] | ((unsigned)o[3] << 16);
  *(uint2*)&dst[t * 4] = pv;
}

// ---------------- transpose+convert: f32 (R,C) -> bf16 (C,R) with out leading dim ----------------
__global__ __launch_bounds__(256) void transpose_k(
    const float* __restrict__ in, u16* __restrict__ out, int R, int C, int ldo, float scale)
{
  __shared__ float tile[64][65];
  const int c0 = blockIdx.x * 64, r0 = blockIdx.y * 64;
  const int t = threadIdx.x;
  const int tr = t >> 4, tc = (t & 15) * 4;
  #pragma unroll
  for (int i = 0; i < 4; ++i) {
    int r = tr + i * 16;
    float4 v = *(const float4*)&in[(size_t)(r0 + r) * C + c0 + tc];
    tile[r][tc + 0] = v.x; tile[r][tc + 1] = v.y; tile[r][tc + 2] = v.z; tile[r][tc + 3] = v.w;
  }
  __syncthreads();
  #pragma unroll
  for (int i = 0; i < 2; ++i) {
    int c  = (t >> 3) + i * 32;
    int rb = (t & 7) * 8;
    union { u16 s[8]; uint4 v; } pk;
    #pragma unroll
    for (int u = 0; u < 8; ++u) pk.s[u] = f2bf(tile[rb + u][c] * scale);
    *(uint4*)&out[(size_t)(c0 + c) * ldo + r0 + rb] = pk.v;
  }
}

// ---------------- Wff1 transpose with (a,gate) fragment interleave ----------------
__global__ __launch_bounds__(256) void transpose_ff1(
    const float* __restrict__ in, u16* __restrict__ out)
{
  __shared__ float tile[64][65];
  const int c0 = blockIdx.x * 64, r0 = blockIdx.y * 64;
  const int t = threadIdx.x;
  const int tr = t >> 4, tc = (t & 15) * 4;
  #pragma unroll
  for (int i = 0; i < 4; ++i) {
    int r = tr + i * 16;
    float4 v = *(const float4*)&in[(size_t)(r0 + r) * 8192 + c0 + tc];
    tile[r][tc + 0] = v.x; tile[r][tc + 1] = v.y; tile[r][tc + 2] = v.z; tile[r][tc + 3] = v.w;
  }
  __syncthreads();
  #pragma unroll
  for (int i = 0; i < 2; ++i) {
    int c  = (t >> 3) + i * 32;
    int rb = (t & 7) * 8;
    const int gc = c0 + c;
    int j, add16;
    if (gc < 4096) { j = gc; add16 = 0; } else { j = gc - 4096; add16 = 16; }
    const int row = 1024 + ((j >> 7) << 8) + (((j >> 5) & 3) << 6) + (((j >> 4) & 1) << 5) + add16 + (j & 15);
    union { u16 s[8]; uint4 v; } pk;
    #pragma unroll
    for (int u = 0; u < 8; ++u) pk.s[u] = f2bf(tile[rb + u][c]);
    *(uint4*)&out[(size_t)row * 1024 + r0 + rb] = pk.v;
  }
}

// =============== 8-phase 256x256 GEMM (BK=64, 8 waves, 2-deep dbuf) ===============
#define MM1(MQ, M, NN, BF) acc[MQ][M][NN] = __builtin_amdgcn_mfma_f32_16x16x32_bf16(af##M, BF, acc[MQ][M][NN], 0, 0, 0)
#define MFMA16(MQ, KS) \
  MM1(MQ,0,0,bf##KS##0); MM1(MQ,0,1,bf##KS##1); MM1(MQ,0,2,bf##KS##2); MM1(MQ,0,3,bf##KS##3); \
  MM1(MQ,1,0,bf##KS##0); MM1(MQ,1,1,bf##KS##1); MM1(MQ,1,2,bf##KS##2); MM1(MQ,1,3,bf##KS##3); \
  MM1(MQ,2,0,bf##KS##0); MM1(MQ,2,1,bf##KS##1); MM1(MQ,2,2,bf##KS##2); MM1(MQ,2,3,bf##KS##3); \
  MM1(MQ,3,0,bf##KS##0); MM1(MQ,3,1,bf##KS##1); MM1(MQ,3,2,bf##KS##2); MM1(MQ,3,3,bf##KS##3)

#define SG_A(SBUF, H, KT) do { \
    GLDS16(gA[H][0] + ((size_t)(KT) << 6), SBUF + ((H) * 64 + w16o) * 64); \
    GLDS16(gA[H][1] + ((size_t)(KT) << 6), SBUF + ((H) * 64 + w16o + 8) * 64); \
  } while (0)
#define SG_B(SBUF, H, KT) do { \
    GLDS16(gB[H][0] + ((size_t)(KT) << 6), SBUF + ((H) * 128 + w16o2) * 64); \
    GLDS16(gB[H][1] + ((size_t)(KT) << 6), SBUF + ((H) * 128 + w16o2 + 8) * 64); \
  } while (0)

#define DS_B(PB_) do { \
  bf00 = *(const short8*)(PB_ + 0    + cks0); bf01 = *(const short8*)(PB_ + 1024 + cks0); \
  bf02 = *(const short8*)(PB_ + 2048 + cks0); bf03 = *(const short8*)(PB_ + 3072 + cks0); \
  bf10 = *(const short8*)(PB_ + 0    + cks1); bf11 = *(const short8*)(PB_ + 1024 + cks1); \
  bf12 = *(const short8*)(PB_ + 2048 + cks1); bf13 = *(const short8*)(PB_ + 3072 + cks1); \
} while (0)

#define P_CORE(PA_, MQ, KS, STAGE_STMT, PREB_STMT, GATE_STMT) do { \
  af0 = *(const short8*)(PA_ + (MQ) * 4096 + 0    + cks##KS); \
  af1 = *(const short8*)(PA_ + (MQ) * 4096 + 1024 + cks##KS); \
  af2 = *(const short8*)(PA_ + (MQ) * 4096 + 2048 + cks##KS); \
  af3 = *(const short8*)(PA_ + (MQ) * 4096 + 3072 + cks##KS); \
  STAGE_STMT; \
  PREB_STMT; \
  __builtin_amdgcn_s_barrier(); \
  asm volatile("s_waitcnt lgkmcnt(0)" ::: "memory"); \
  __builtin_amdgcn_s_setprio(1); \
  MFMA16(MQ, KS); \
  __builtin_amdgcn_s_setprio(0); \
  GATE_STMT; \
  __builtin_amdgcn_s_barrier(); \
} while (0)

#define GATE6 asm volatile("s_waitcnt vmcnt(6)" ::: "memory")
#define GATE0 asm volatile("s_waitcnt vmcnt(0)" ::: "memory")
#define HINT8 asm volatile("s_waitcnt lgkmcnt(8)" ::: "memory")

// MODE 2: qff fused epilogue (q bf16 + silu pair-fused h). MODE 3: bf16 split-K partials.
template<int MODE, int ORDER>
__global__ __launch_bounds__(512, 2) void gemm8p(
    const u16* __restrict__ A, const u16* __restrict__ BT, void* __restrict__ C,
    void* __restrict__ C2, int M, int N, int Ktot, int Kslice)
{
  __shared__ u16 sh[2][2][16384]; // [buf][A/B][256*64]
  const int nbn = N >> 8, nbm = M >> 8;
  const int nwg = gridDim.x;
  const int bid = blockIdx.x;
  const int o = (bid & 7) * (nwg >> 3) + (bid >> 3);  // chunked bijective XCD map (nwg%8==0)
  int bm, bn;
  if constexpr (ORDER == 0) { bm = o % nbm; bn = o / nbm; }  // B-strip per XCD
  else                      { bn = o % nbn; bm = o / nbn; }  // A-panels per XCD
  const int kbase = blockIdx.y * Kslice;
  const int NI = Kslice >> 7;

  const int t = threadIdx.x, w = t >> 6, lane = t & 63;
  const int wr = w >> 2, wc = w & 3;
  const int lr = lane & 15, lg = lane >> 4;
  const int r8 = lane >> 3, ch = lane & 7;
  const int clog = ch ^ r8;
  const int w16o  = w * 16 + ((w >= 4) ? 64 : 0);
  const int w16o2 = w * 16;

  const u16* gA[2][2]; const u16* gB[2][2];
  #pragma unroll
  for (int h = 0; h < 2; ++h)
    #pragma unroll
    for (int qq = 0; qq < 2; ++qq) {
      gA[h][qq] = A  + (size_t)(bm * 256 + h * 64  + w16o  + qq * 8 + r8) * Ktot + kbase + clog * 8;
      gB[h][qq] = BT + (size_t)(bn * 256 + h * 128 + w16o2 + qq * 8 + r8) * Ktot + kbase + clog * 8;
    }
  u16* sA0 = &sh[0][0][0]; u16* sA1 = &sh[1][0][0];
  u16* sB0 = &sh[0][1][0]; u16* sB1 = &sh[1][1][0];
  const int cks0 = ((0 + lg) ^ (lr & 7)) * 8;
  const int cks1 = ((4 + lg) ^ (lr & 7)) * 8;
  const u16* pA_b0 = sA0 + (wr * 128 + lr) * 64;
  const u16* pA_b1 = sA1 + (wr * 128 + lr) * 64;
  const u16* pB_b0 = sB0 + (wc * 64 + lr) * 64;
  const u16* pB_b1 = sB1 + (wc * 64 + lr) * 64;

  f32x4 acc[2][4][4];
  const f32x4 z4 = { 0.f, 0.f, 0.f, 0.f };
  #pragma unroll
  for (int a = 0; a < 2; ++a)
    #pragma unroll
    for (int b = 0; b < 4; ++b)
      #pragma unroll
      for (int c = 0; c < 4; ++c) acc[a][b][c] = z4;
  short8 af0, af1, af2, af3;
  short8 bf00, bf01, bf02, bf03, bf10, bf11, bf12, bf13;

  SG_B(sB0, 0, 0); SG_B(sB0, 1, 0); SG_A(sA0, 0, 0); SG_A(sA0, 1, 0);
  SG_B(sB1, 0, 1); SG_B(sB1, 1, 1); SG_A(sA1, 0, 1);
  GATE6;
  __builtin_amdgcn_s_barrier();

  for (int i = 0; i < NI; ++i) {
    const int k2 = 2 * i;
    const bool st = (i < NI - 1);
    DS_B(pB_b0);
    P_CORE(pA_b0, 0, 0, SG_A(sA1, 1, k2 + 1), HINT8, );
    P_CORE(pA_b0, 1, 0, if (st) SG_B(sB0, 0, k2 + 2), , );
    P_CORE(pA_b0, 0, 1, if (st) SG_B(sB0, 1, k2 + 2), , );
    P_CORE(pA_b0, 1, 1, if (st) SG_A(sA0, 0, k2 + 2), ,
           if (st) { GATE6; } else { GATE0; });
    DS_B(pB_b1);
    P_CORE(pA_b1, 0, 0, if (st) SG_A(sA0, 1, k2 + 2), HINT8, );
    P_CORE(pA_b1, 1, 0, if (st) SG_B(sB1, 0, k2 + 3), , );
    P_CORE(pA_b1, 0, 1, if (st) SG_B(sB1, 1, k2 + 3), , );
    P_CORE(pA_b1, 1, 1, if (st) SG_A(sA1, 0, k2 + 3), ,
           if (st) { GATE6; });
  }

  if constexpr (MODE == 3) {
    u16* Co = (u16*)C + (size_t)blockIdx.y * M * N;
    #pragma unroll
    for (int mq = 0; mq < 2; ++mq)
      #pragma unroll
      for (int m = 0; m < 4; ++m)
        #pragma unroll
        for (int n = 0; n < 4; ++n)
          #pragma unroll
          for (int rr = 0; rr < 4; ++rr) {
            const int row = bm * 256 + wr * 128 + mq * 64 + m * 16 + lg * 4 + rr;
            const int col = bn * 256 + wc * 64 + n * 16 + lr;
            Co[(size_t)row * N + col] = f2bf(acc[mq][m][n][rr]);
          }
  } else {
    if (bn < 4) {
      u16* Co = (u16*)C; // qbuf, stride 1024
      #pragma unroll
      for (int mq = 0; mq < 2; ++mq)
        #pragma unroll
        for (int m = 0; m < 4; ++m)
          #pragma unroll
          for (int n = 0; n < 4; ++n)
            #pragma unroll
            for (int rr = 0; rr < 4; ++rr) {
              const int row = bm * 256 + wr * 128 + mq * 64 + m * 16 + lg * 4 + rr;
              const int col = bn * 256 + wc * 64 + n * 16 + lr;
              Co[(size_t)row * 1024 + col] = f2bf(acc[mq][m][n][rr]);
            }
    } else {
      u16* Ho = (u16*)C2; // aoh, stride 5120, h starts at col 1024
      const int colb = 1024 + (bn - 4) * 128 + wc * 32 + lr;
      #pragma unroll
      for (int mq = 0; mq < 2; ++mq)
        #pragma unroll
        for (int m = 0; m < 4; ++m)
          #pragma unroll
          for (int rr = 0; rr < 4; ++rr) {
            const int row = bm * 256 + wr * 128 + mq * 64 + m * 16 + lg * 4 + rr;
            #pragma unroll
            for (int n2 = 0; n2 < 2; ++n2) {
              const float a = acc[mq][m][2 * n2][rr];
              const float gt = acc[mq][m][2 * n2 + 1][rr];
              const float h = a * gt / (1.0f + __expf(-gt));
              Ho[(size_t)row * 5120 + colb + n2 * 16] = f2bf(h);
            }
          }
    }
  }
}

// ---------------- split-K GEMM 128x128 (kv projection), bf16 partials ----------------
__global__ __launch_bounds__(256) void gemm_bt_sk(
    const u16* __restrict__ A, const u16* __restrict__ BT, u16* __restrict__ Cp,
    int M, int N, int Kslice, int Ktot)
{
  __shared__ u16 As[128 * 32];
  __shared__ u16 Bs[128 * 32];
  const int bm = blockIdx.y, bn = blockIdx.x, z = blockIdx.z;
  const int t = threadIdx.x;
  const int w = t >> 6, lane = t & 63;
  const int wr = w >> 1, wc = w & 1;
  const int lr = lane & 15, lkc = lane >> 4;

  f32x4 acc[4][4];
  const f32x4 z4 = { 0.f, 0.f, 0.f, 0.f };
  #pragma unroll
  for (int mi = 0; mi < 4; ++mi)
    #pragma unroll
    for (int ni = 0; ni < 4; ++ni) acc[mi][ni] = z4;

  const int kbase = z * Kslice;
  const int i0 = t, i1 = t + 256;
  const int r0 = i0 >> 2, k0 = swz4(r0, i0 & 3) * 8;
  const int r1 = i1 >> 2, k1 = swz4(r1, i1 & 3) * 8;
  const u16* a0 = A + (size_t)(bm * 128 + r0) * Ktot + kbase + k0;
  const u16* a1 = A + (size_t)(bm * 128 + r1) * Ktot + kbase + k1;
  const u16* b0 = BT + (size_t)(bn * 128 + r0) * Ktot + kbase + k0;
  const u16* b1 = BT + (size_t)(bn * 128 + r1) * Ktot + kbase + k1;
  u16* As0 = As + (size_t)w * 512;
  u16* As1 = As + (size_t)(w + 4) * 512;
  u16* Bs0 = Bs + (size_t)w * 512;
  u16* Bs1 = Bs + (size_t)(w + 4) * 512;

  const int nk = Kslice >> 5;
  for (int kt = 0; kt < nk; ++kt) {
    __syncthreads();
    GLDS16(a0, As0); GLDS16(a1, As1); GLDS16(b0, Bs0); GLDS16(b1, Bs1);
    a0 += 32; a1 += 32; b0 += 32; b1 += 32;
    __syncthreads();
    short8 af[4], bf[4];
    #pragma unroll
    for (int mi = 0; mi < 4; ++mi) {
      int row = wr * 64 + mi * 16 + lr;
      af[mi] = *(const short8*)&As[row * 32 + swz4(row, lkc) * 8];
    }
    #pragma unroll
    for (int ni = 0; ni < 4; ++ni) {
      int row = wc * 64 + ni * 16 + lr;
      bf[ni] = *(const short8*)&Bs[row * 32 + swz4(row, lkc) * 8];
    }
    #pragma unroll
    for (int mi = 0; mi < 4; ++mi)
      #pragma unroll
      for (int ni = 0; ni < 4; ++ni)
        acc[mi][ni] = __builtin_amdgcn_mfma_f32_16x16x32_bf16(af[mi], bf[ni], acc[mi][ni], 0, 0, 0);
  }

  u16* Cz = Cp + (size_t)z * M * N;
  const int row0 = bm * 128 + wr * 64, col0 = bn * 128 + wc * 64;
  const int rsub = (lane >> 4) * 4;
  #pragma unroll
  for (int mi = 0; mi < 4; ++mi)
    #pragma unroll
    for (int ni = 0; ni < 4; ++ni)
      #pragma unroll
      for (int r = 0; r < 4; ++r)
        Cz[(size_t)(row0 + mi * 16 + rsub + r) * N + (col0 + ni * 16 + lr)] = f2bf(acc[mi][ni][r]);
}

// ---------------- reduce 8 bf16 partials (4096x128) -> bf16 ----------------
__global__ __launch_bounds__(256) void reduce_kv(const u16* __restrict__ part, u16* __restrict__ out)
{
  const size_t base = ((size_t)blockIdx.x * 256 + threadIdx.x) * 8;
  float s[8] = { 0.f, 0.f, 0.f, 0.f, 0.f, 0.f, 0.f, 0.f };
  #pragma unroll
  for (int zz = 0; zz < 8; ++zz) {
    const short8 v = *(const short8*)&part[(size_t)zz * 524288 + base];
    #pragma unroll
    for (int i = 0; i < 8; ++i) s[i] += bf2f((u16)v[i]);
  }
  union { u16 o[8]; uint4 v; } pk;
  #pragma unroll
  for (int i = 0; i < 8; ++i) pk.o[i] = f2bf(s[i]);
  *(uint4*)&out[base] = pk.v;
}

// ---------------- out = sum of 4 bf16 partials (4096x1024) -> f32 ----------------
__global__ __launch_bounds__(256) void reduce_out(const u16* __restrict__ part, float* __restrict__ out)
{
  const size_t base = ((size_t)blockIdx.x * 256 + threadIdx.x) * 8;
  float s[8] = { 0.f, 0.f, 0.f, 0.f, 0.f, 0.f, 0.f, 0.f };
  #pragma unroll
  for (int zz = 0; zz < 4; ++zz) {
    const short8 v = *(const short8*)&part[(size_t)zz * 4194304 + base];
    #pragma unroll
    for (int i = 0; i < 8; ++i) s[i] += bf2f((u16)v[i]);
  }
  f32x4 lo = { s[0], s[1], s[2], s[3] };
  f32x4 hi = { s[4], s[5], s[6], s[7] };
  *(f32x4*)&out[base] = lo;
  *(f32x4*)&out[base + 4] = hi;
}

// ---------------- flash cross-attention (multi-query: 1 KV head) ----------------
// 64 q-rows per wave (2 q32 tiles), 4 heads/block, grid (N/64, H/4, B) = 256 blocks.
// T13 defer-max: skip max-update + O-rescale when tile max <= m + 8 (wave-uniform).
__global__ __launch_bounds__(256) void attn_kernel(
    const u16* __restrict__ q, const u16* __restrict__ kv, u16* __restrict__ o)
{
  __shared__ u16 Ks[128 * 64];
  __shared__ u16 Vt[64 * 128];
  __shared__ u16 Ps[4][32 * 128];
  const int b = blockIdx.z, hb = blockIdx.y, qb = blockIdx.x;
  const int t = threadIdx.x, w = t >> 6, lane = t & 63;
  const int q32 = lane & 31, hl = lane >> 5;
  const int hd = hb * 4 + w;

  const size_t qbase = (size_t)b * 2048 + qb * 64;
  short8 qa[2][4];
  #pragma unroll
  for (int t32 = 0; t32 < 2; ++t32)
    #pragma unroll
    for (int dq = 0; dq < 4; ++dq)
      qa[t32][dq] = *(const short8*)&q[(qbase + t32 * 32 + q32) * 1024 + hd * 64 + dq * 16 + hl * 8];

  f32x16 oacc[2][2];
  #pragma unroll
  for (int i = 0; i < 2; ++i)
    #pragma unroll
    for (int j = 0; j < 2; ++j)
      #pragma unroll
      for (int r = 0; r < 16; ++r) oacc[i][j][r] = 0.f;
  float m_[2] = { -1e30f, -1e30f }, l_[2] = { 0.f, 0.f };

  const size_t kvb = (size_t)b * 2048 * 128;
  const int vd0 = (t & 7) * 8;
  const int vodd = (t >> 3) & 1;
  u16* Pw = &Ps[w][0];

  for (int jt = 0; jt < 16; ++jt) {
    __syncthreads();
    #pragma unroll
    for (int n = 0; n < 4; ++n) {
      const int cc = n * 256 + w * 64;
      const int ccl = cc + lane;
      const int row = ccl >> 3, lc = (ccl & 7) ^ (row & 7);
      GLDS16(&kv[kvb + (size_t)(jt * 128 + row) * 128 + lc * 8], Ks + (size_t)cc * 8);
    }
    #pragma unroll
    for (int c = 0; c < 4; ++c) {
      const int seg = c * 256 + t;
      const int vj = seg >> 3;
      const int jp = vj >> 1;
      const uint4 vv = *(const uint4*)&kv[kvb + (size_t)(jt * 128 + vj) * 128 + 64 + vd0];
      uint4 pvv;
      pvv.x = __shfl_xor((int)vv.x, 8);
      pvv.y = __shfl_xor((int)vv.y, 8);
      pvv.z = __shfl_xor((int)vv.z, 8);
      pvv.w = __shfl_xor((int)vv.w, 8);
      const unsigned ow[4] = { vv.x, vv.y, vv.z, vv.w };
      const unsigned pw[4] = { pvv.x, pvv.y, pvv.z, pvv.w };
      if (!vodd) {
        #pragma unroll
        for (int u = 0; u < 4; ++u) {
          const int d = vd0 + u;
          const unsigned own = (u & 1) ? (ow[u >> 1] >> 16) : (ow[u >> 1] & 0xffffu);
          const unsigned par = (u & 1) ? (pw[u >> 1] >> 16) : (pw[u >> 1] & 0xffffu);
          const int byteoff = d * 256 + ((4 * jp) ^ (((d & 7) ^ ((d >> 3) & 7)) << 4));
          *(unsigned*)((char*)Vt + byteoff) = own | (par << 16);
        }
      } else {
        #pragma unroll
        for (int u = 0; u < 4; ++u) {
          const int ue = u + 4;
          const int d = vd0 + ue;
          const unsigned own = (ue & 1) ? (ow[ue >> 1] >> 16) : (ow[ue >> 1] & 0xffffu);
          const unsigned par = (ue & 1) ? (pw[ue >> 1] >> 16) : (pw[ue >> 1] & 0xffffu);
          const int byteoff = d * 256 + ((4 * jp) ^ (((d & 7) ^ ((d >> 3) & 7)) << 4));
          *(unsigned*)((char*)Vt + byteoff) = par | (own << 16);
        }
      }
    }
    __syncthreads();

    #pragma unroll
    for (int t32 = 0; t32 < 2; ++t32) {
      f32x16 s[4];
      #pragma unroll
      for (int j32 = 0; j32 < 4; ++j32)
        #pragma unroll
        for (int r = 0; r < 16; ++r) s[j32][r] = 0.f;
      #pragma unroll
      for (int j32 = 0; j32 < 4; ++j32) {
        const int row = j32 * 32 + q32;
        #pragma unroll
        for (int dq = 0; dq < 4; ++dq) {
          const int slot = (dq * 2 + hl) ^ (row & 7);
          const short8 kf = *(const short8*)&Ks[row * 64 + slot * 8];
          s[j32] = __builtin_amdgcn_mfma_f32_32x32x16_bf16(kf, qa[t32][dq], s[j32], 0, 0, 0);
        }
      }
      float mt = -1e30f;
      #pragma unroll
      for (int j32 = 0; j32 < 4; ++j32)
        #pragma unroll
        for (int r = 0; r < 16; ++r) mt = fmaxf(mt, s[j32][r]);
      mt = fmaxf(mt, __shfl_xor(mt, 32));
      const bool noresc = (bool)__all(mt <= m_[t32] + 8.0f);
      float nm = m_[t32];
      if (!noresc) {
        nm = fmaxf(m_[t32], mt);
        const float alpha = __expf(m_[t32] - nm);
        m_[t32] = nm;
        l_[t32] *= alpha;
        #pragma unroll
        for (int d32 = 0; d32 < 2; ++d32)
          #pragma unroll
          for (int r = 0; r < 16; ++r) oacc[t32][d32][r] *= alpha;
      }
      float lsum = 0.f;
      #pragma unroll
      for (int j32 = 0; j32 < 4; ++j32) {
        float p[16];
        #pragma unroll
        for (int r = 0; r < 16; ++r) { p[r] = __expf(s[j32][r] - nm); lsum += p[r]; }
        #pragma unroll
        for (int g = 0; g < 4; ++g) {
          const unsigned lo = cvtpk(p[4 * g + 0], p[4 * g + 1]);
          const unsigned hi = cvtpk(p[4 * g + 2], p[4 * g + 3]);
          const int j2 = j32 * 64 + 16 * g + 8 * hl;
          const int byteoff = q32 * 256 + (j2 ^ ((q32 & 7) << 4));
          uint2 wv; wv.x = lo; wv.y = hi;
          *(uint2*)((char*)Pw + byteoff) = wv;
        }
      }
      lsum += __shfl_xor(lsum, 32);
      l_[t32] += lsum;
      short8 pf[8];
      #pragma unroll
      for (int kk = 0; kk < 8; ++kk) {
        const int byteoff = q32 * 256 + ((kk * 32 + hl * 16) ^ ((q32 & 7) << 4));
        pf[kk] = *(const short8*)((const char*)Pw + byteoff);
      }
      #pragma unroll
      for (int d32 = 0; d32 < 2; ++d32) {
        const int dr = d32 * 32 + q32;
        const int vswz = ((dr & 7) ^ ((dr >> 3) & 7)) << 4;
        #pragma unroll
        for (int kk = 0; kk < 8; ++kk) {
          const int byteoff = dr * 256 + ((kk * 32 + hl * 16) ^ vswz);
          const short8 vf = *(const short8*)((const char*)Vt + byteoff);
          oacc[t32][d32] = __builtin_amdgcn_mfma_f32_32x32x16_bf16(vf, pf[kk], oacc[t32][d32], 0, 0, 0);
        }
      }
    }
  }

  float* Ot = (float*)Pw;
  #pragma unroll
  for (int t32 = 0; t32 < 2; ++t32) {
    const float inv = 1.0f / l_[t32];
    #pragma unroll
    for (int d32 = 0; d32 < 2; ++d32) {
      #pragma unroll
      for (int r = 0; r < 16; ++r) {
        const int d = (r & 3) + 8 * (r >> 2) + 4 * hl;
        const int byteoff = q32 * 128 + ((4 * d) ^ ((q32 & 7) << 4));
        *(float*)((char*)Ot + byteoff) = oacc[t32][d32][r] * inv;
      }
      const int qr = lane >> 1, dc = (lane & 1) * 16;
      union { u16 s[16]; uint4 v[2]; } ob;
      #pragma unroll
      for (int cch = 0; cch < 4; ++cch) {
        const int byteoff = qr * 128 + ((4 * (dc + 4 * cch)) ^ ((qr & 7) << 4));
        const f32x4 vv = *(const f32x4*)((const char*)Ot + byteoff);
        ob.s[cch * 4 + 0] = f2bf(vv[0]);
        ob.s[cch * 4 + 1] = f2bf(vv[1]);
        ob.s[cch * 4 + 2] = f2bf(vv[2]);
        ob.s[cch * 4 + 3] = f2bf(vv[3]);
      }
      u16* orow = &o[(qbase + t32 * 32 + qr) * 5120 + hd * 64 + d32 * 32 + dc];
      *(uint4*)orow = ob.v[0];
      *(uint4*)(orow + 8) = ob.v[1];
    }
  }
}

extern "C" void kernel_launch(void* const* d_in, const int* in_sizes, int n_in,
                              void* d_out, int out_size, void* d_ws, size_t ws_size,
                              hipStream_t stream)
{
  const float* x    = (const float*)d_in[0];
  const float* ctx  = (const float*)d_in[1];
  const float* ng   = (const float*)d_in[2];
  const float* nb   = (const float*)d_in[3];
  const float* cg   = (const float*)d_in[4];
  const float* cb   = (const float*)d_in[5];
  const float* Wq   = (const float*)d_in[6];
  const float* Wkv  = (const float*)d_in[7];
  const float* Wo   = (const float*)d_in[8];
  const float* Wff1 = (const float*)d_in[9];
  const float* Wff2 = (const float*)d_in[10];

  u16* p = (u16*)d_ws;
  u16* W1T   = p; p += (size_t)9216 * 1024;
  u16* WkvT  = p; p += (size_t)128 * 1024;
  u16* WcT   = p; p += (size_t)1024 * 5120;
  u16* kvbuf = p; p += (size_t)4096 * 128;
  u16* aoh   = p; p += (size_t)4096 * 5120;
  u16* xn    = p; p += (size_t)4096 * 1024;
  u16* cn    = p; p += (size_t)4096 * 1024;
  u16* qbuf  = p; p += (size_t)4096 * 1024;
  u16* kvpart = W1T;   // 8 MB bf16 over W1T (dead after qff GEMM)
  u16* ffpart = xn;    // 32 MB bf16 over xn|cn|qbuf + tail (dead by final GEMM)
  (void)in_sizes; (void)n_in; (void)out_size; (void)ws_size;

  ln_kernel<<<8192, 256, 0, stream>>>(x, ctx, ng, nb, cg, cb, xn, cn);

  transpose_k<<<dim3(16, 16),  256, 0, stream>>>(Wq,   W1T,        1024, 1024, 1024, 0.125f);
  transpose_ff1<<<dim3(128, 16), 256, 0, stream>>>(Wff1, W1T);
  transpose_k<<<dim3(2, 16),   256, 0, stream>>>(Wkv,  WkvT,       1024, 128,  1024, 1.0f);
  transpose_k<<<dim3(16, 16),  256, 0, stream>>>(Wo,   WcT,        1024, 1024, 5120, 1.0f);
  transpose_k<<<dim3(16, 64),  256, 0, stream>>>(Wff2, WcT + 1024, 4096, 1024, 5120, 1.0f);

  // fused: qbuf = xn@Wq*scale ; aoh[:,1024:] = silu(xn@Wff1); ORDER 0 (B-strip per XCD)
  gemm8p<2, 0><<<dim3(576), 512, 0, stream>>>(xn, W1T, qbuf, aoh, 4096, 9216, 1024, 1024);
  // kv = cn @ Wkv, split-K 8 (bf16 partials over dead W1T), reduce to bf16
  gemm_bt_sk<<<dim3(1, 32, 8), 256, 0, stream>>>(cn, WkvT, kvpart, 4096, 128, 128, 1024);
  reduce_kv<<<256, 256, 0, stream>>>(kvpart, kvbuf);
  // attention -> aoh[:,0:1024]
  attn_kernel<<<dim3(32, 4, 2), 256, 0, stream>>>(qbuf, kvbuf, aoh);
  // out = aoh @ [Wo ; Wff2], split-K 4, bf16 partials; ORDER 1 (A-panels per XCD)
  gemm8p<3, 1><<<dim3(64, 4), 512, 0, stream>>>(aoh, WcT, ffpart, nullptr, 4096, 1024, 5120, 1280);
  reduce_out<<<2048, 256, 0, stream>>>(ffpart, (float*)d_out);
}